// Round 3
// baseline (647.678 us; speedup 1.0000x reference)
//
#include <hip/hip_runtime.h>
#include <hip/hip_fp16.h>

typedef _Float16 f16x8 __attribute__((ext_vector_type(8)));
typedef float f32x4 __attribute__((ext_vector_type(4)));

#define DEV __device__ __forceinline__

typedef const __attribute__((address_space(1))) void gvoid_t;
typedef __attribute__((address_space(3))) void lvoid_t;

DEV void gload16(const void* g, void* l) {
  __builtin_amdgcn_global_load_lds((gvoid_t*)g, (lvoid_t*)l, 16, 0, 0);
}

DEV f32x4 mfma16(f16x8 a, f16x8 b, f32x4 c) {
  return __builtin_amdgcn_mfma_f32_16x16x32_f16(a, b, c, 0, 0, 0);
}

// ---------------- f32 -> f16 convert ----------------
__global__ __launch_bounds__(256) void cvt_kernel(const float* __restrict__ s,
                                                  __half* __restrict__ d, int n4) {
  int stride = gridDim.x * 256;
  for (int i = blockIdx.x * 256 + threadIdx.x; i < n4; i += stride) {
    float4 v = ((const float4*)s)[i];
    __align__(8) __half a[4] = {__float2half(v.x), __float2half(v.y),
                                __float2half(v.z), __float2half(v.w)};
    *((uint2*)(d + (size_t)i * 4)) = *((uint2*)a);
  }
}

// ---------------- RMSNorm (row-wise, f32 in -> f16 out) ----------------
template <int W>
__global__ __launch_bounds__(256) void rms_kernel(const float* __restrict__ x, int ldx,
                                                  const float* __restrict__ wgt,
                                                  __half* __restrict__ y, int ldy) {
  const int row = blockIdx.x, tid = threadIdx.x;
  const float4* xr = (const float4*)(x + (size_t)row * ldx);
  float4 v0 = make_float4(0.f, 0.f, 0.f, 0.f), v1 = v0;
  if (tid < W / 4) v0 = xr[tid];
  if (tid + 256 < W / 4) v1 = xr[tid + 256];
  float ss = v0.x * v0.x + v0.y * v0.y + v0.z * v0.z + v0.w * v0.w +
             v1.x * v1.x + v1.y * v1.y + v1.z * v1.z + v1.w * v1.w;
  for (int mm = 1; mm <= 32; mm <<= 1) ss += __shfl_xor(ss, mm);
  __shared__ float sred[4];
  if ((tid & 63) == 0) sred[tid >> 6] = ss;
  __syncthreads();
  float rs = 1.0f / sqrtf((sred[0] + sred[1] + sred[2] + sred[3]) * (1.0f / (float)W) + 1e-6f);
  __half* yr = y + (size_t)row * ldy;
  if (tid < W / 4) {
    int j = tid * 4;
    yr[j + 0] = __float2half(wgt[j + 0] * v0.x * rs);
    yr[j + 1] = __float2half(wgt[j + 1] * v0.y * rs);
    yr[j + 2] = __float2half(wgt[j + 2] * v0.z * rs);
    yr[j + 3] = __float2half(wgt[j + 3] * v0.w * rs);
  }
  if (tid + 256 < W / 4) {
    int j = (tid + 256) * 4;
    yr[j + 0] = __float2half(wgt[j + 0] * v1.x * rs);
    yr[j + 1] = __float2half(wgt[j + 1] * v1.y * rs);
    yr[j + 2] = __float2half(wgt[j + 2] * v1.z * rs);
    yr[j + 3] = __float2half(wgt[j + 3] * v1.w * rs);
  }
}

// ---------------- YaRN cos/sin table (double precision) ----------------
// dim=64, base=50000, factor=32, orig_max=4096 -> low=8, high=20
__global__ __launch_bounds__(256) void rope_table_kernel(const int* __restrict__ pos,
                                                         float2* __restrict__ cs) {
  int i = blockIdx.x * 256 + threadIdx.x;  // 2048*32
  int row = i >> 5, j = i & 31;
  double f = (double)j * (1.0 / 32.0);
  double fe = exp(-f * 10.81977828441028);  // BASE^-f
  double fi = fe * (1.0 / 32.0);
  double ramp = fmin(fmax(((double)j - 8.0) * (1.0 / 12.0), 0.0), 1.0);
  double inv = fi * ramp + fe * (1.0 - ramp);
  double ang = (double)pos[row] * inv;
  cs[i] = make_float2((float)cos(ang), (float)sin(ang));
}

// rope for q_pe: qpe [2048][32*64] f16 -> Q [h][row][128..191], scaled
__global__ __launch_bounds__(256) void rope_q_kernel(const __half* __restrict__ qpe,
                                                     const float2* __restrict__ cs,
                                                     __half* __restrict__ Qb, float qscale) {
  int i = blockIdx.x * 256 + threadIdx.x;  // 2048*32*32
  int row = i >> 10, rem = i & 1023, h = rem >> 5, j = rem & 31;
  float x0 = __half2float(qpe[(size_t)row * 2048 + h * 64 + 2 * j]);
  float x1 = __half2float(qpe[(size_t)row * 2048 + h * 64 + 2 * j + 1]);
  float2 c = cs[row * 32 + j];
  float o0 = (x0 * c.x - x1 * c.y) * qscale;
  float o1 = (x1 * c.x + x0 * c.y) * qscale;
  __half* dst = Qb + ((size_t)h * 2048 + row) * 192;
  dst[128 + j] = __float2half(o0);
  dst[160 + j] = __float2half(o1);
}

// rope for k_pe (from ckv f32 cols 512..575), broadcast to all 32 heads
__global__ __launch_bounds__(256) void rope_k_kernel(const float* __restrict__ ckv,
                                                     const float2* __restrict__ cs,
                                                     __half* __restrict__ Kb) {
  int i = blockIdx.x * 256 + threadIdx.x;  // 2048*32*32
  int row = i >> 10, rem = i & 1023, h = rem >> 5, j = rem & 31;
  float x0 = ckv[(size_t)row * 576 + 512 + 2 * j];
  float x1 = ckv[(size_t)row * 576 + 512 + 2 * j + 1];
  float2 c = cs[row * 32 + j];
  __half* dst = Kb + ((size_t)h * 2048 + row) * 192;
  dst[128 + j] = __float2half(x0 * c.x - x1 * c.y);
  dst[160 + j] = __float2half(x1 * c.x + x0 * c.y);
}

// ---------------- GEMM: C[M,N] = A[M,K](f16) x B[N,K](f16)^T ----------------
// 128x128 tile, BK=32, 4 waves 2x2, 16x16x32 MFMA.  EPI: 0=f32 store,
// 2=q_b split (Q nope *scale + qpe scratch), 3=kv_b split (K nope + V^T)
template <int EPI>
__global__ __launch_bounds__(256) void gemm128(const __half* __restrict__ A, int lda,
                                               const __half* __restrict__ B, int K, int Ncols,
                                               float* __restrict__ Cf, int ldc,
                                               __half* __restrict__ O1, __half* __restrict__ O2,
                                               float qscale) {
  __shared__ __align__(16) char As[8192];
  __shared__ __align__(16) char Bs[8192];
  const int tid = threadIdx.x;
  const int lane = tid & 63, w = tid >> 6;
  const int l15 = lane & 15, g = lane >> 4;
  const int wr = w >> 1, wc = w & 1;
  const int m0 = blockIdx.y * 128, n0 = blockIdx.x * 128;
  const int srow = lane >> 2, scol = (lane & 3) * 8;
  f32x4 acc[4][4] = {};

  for (int kt = 0; kt < K; kt += 32) {
    __syncthreads();
#pragma unroll
    for (int cc = 0; cc < 2; ++cc) {
      int c = 2 * w + cc;
      gload16(A + (size_t)(m0 + c * 16 + srow) * lda + kt + scol, As + c * 1024);
      gload16(B + (size_t)(n0 + c * 16 + srow) * K + kt + scol, Bs + c * 1024);
    }
    __syncthreads();
    f16x8 af[4], bf[4];
#pragma unroll
    for (int m = 0; m < 4; ++m)
      af[m] = *(const f16x8*)(As + (wr * 64 + m * 16 + l15) * 64 + g * 16);
#pragma unroll
    for (int n = 0; n < 4; ++n)
      bf[n] = *(const f16x8*)(Bs + (wc * 64 + n * 16 + l15) * 64 + g * 16);
#pragma unroll
    for (int m = 0; m < 4; ++m)
#pragma unroll
      for (int n = 0; n < 4; ++n) acc[m][n] = mfma16(af[m], bf[n], acc[m][n]);
  }

#pragma unroll
  for (int m = 0; m < 4; ++m)
#pragma unroll
    for (int n = 0; n < 4; ++n)
#pragma unroll
      for (int i = 0; i < 4; ++i) {
        int row = m0 + wr * 64 + m * 16 + g * 4 + i;
        int col = n0 + wc * 64 + n * 16 + l15;
        float v = acc[m][n][i];
        if (EPI == 0) {
          if (col < Ncols) Cf[(size_t)row * ldc + col] = v;
        } else if (EPI == 2) {
          int h = col / 192, d = col - h * 192;
          if (d < 128)
            O1[((size_t)h * 2048 + row) * 192 + d] = __float2half(v * qscale);
          else
            O2[(size_t)row * 2048 + h * 64 + (d - 128)] = __float2half(v);
        } else if (EPI == 3) {
          int h = col >> 8, d = col & 255;
          if (d < 128)
            O1[((size_t)h * 2048 + row) * 192 + d] = __float2half(v);
          else
            O2[((size_t)h * 128 + (d - 128)) * 2048 + row] = __float2half(v);
        }
      }
}

// ---------------- Flash attention ----------------
// grid (32 qtiles, 32 heads); 4 waves; QB=64 (16 q-rows/wave); KVB=64.
// Q [h][2048][192] (pre-scaled), K [h][2048][192], Vt [h][128][2048], Out [2048][4096]
__global__ __launch_bounds__(256) void attn_kernel(const __half* __restrict__ Q,
                                                   const __half* __restrict__ K,
                                                   const __half* __restrict__ Vt,
                                                   __half* __restrict__ Out) {
  __shared__ __align__(16) char Klds[64 * 384];
  __shared__ __align__(16) char Vlds[128 * 128];
  __shared__ __align__(16) __half Plds[4][16][72];  // 144B row stride, cols 0..63 used
  const int qt = blockIdx.x, h = blockIdx.y;
  const int q0 = qt * 64;
  const int tid = threadIdx.x, lane = tid & 63, w = tid >> 6;
  const int l15 = lane & 15, g = lane >> 4;

  const __half* Qh = Q + ((size_t)h * 2048 + q0 + w * 16 + l15) * 192;
  f16x8 qf[6];
#pragma unroll
  for (int kc = 0; kc < 6; ++kc) qf[kc] = *(const f16x8*)(Qh + kc * 32 + g * 8);

  const char* Kg = (const char*)(K + (size_t)h * 2048 * 192);
  const char* Vg = (const char*)(Vt + (size_t)h * 128 * 2048);

  f32x4 acc[8] = {};
  float m_i[4], l_i[4];
#pragma unroll
  for (int i = 0; i < 4; ++i) { m_i[i] = -1e30f; l_i[i] = 0.f; }

  for (int kv0 = 0; kv0 <= q0; kv0 += 64) {
    __syncthreads();
    // stage K tile [64][192] f16, XOR-swizzled within rows (8-slot groups)
#pragma unroll
    for (int cc = 0; cc < 6; ++cc) {
      int c = w * 6 + cc;
      int L = c * 64 + lane;
      int row = (L * 2731) >> 16;  // L/24
      int slot = L - row * 24;
      int ss = (slot & ~7) | ((slot ^ row) & 7);
      gload16(Kg + (size_t)(kv0 + row) * 384 + ss * 16, Klds + c * 1024);
    }
    // stage V^T tile [128][64] f16, XOR-swizzled
#pragma unroll
    for (int cc = 0; cc < 4; ++cc) {
      int c = w * 4 + cc;
      int L = c * 64 + lane;
      int d = L >> 3, slot = L & 7;
      int ss = slot ^ (d & 7);
      gload16(Vg + ((size_t)d * 2048 + kv0) * 2 + ss * 16, Vlds + c * 1024);
    }
    __syncthreads();

    // scores: S[16q x 64k] per wave
    f32x4 s[4] = {};
#pragma unroll
    for (int kc = 0; kc < 6; ++kc) {
#pragma unroll
      for (int n = 0; n < 4; ++n) {
        int krow = n * 16 + l15;
        int slot = kc * 4 + g;
        int ss = (slot & ~7) | ((slot ^ krow) & 7);
        f16x8 kf = *(const f16x8*)(Klds + krow * 384 + ss * 16);
        s[n] = mfma16(qf[kc], kf, s[n]);
      }
    }

    const bool diag = (kv0 == q0);
    float ps[4][4];
    float mt[4] = {-1e30f, -1e30f, -1e30f, -1e30f};
#pragma unroll
    for (int n = 0; n < 4; ++n)
#pragma unroll
      for (int i = 0; i < 4; ++i) {
        float v = s[n][i];
        if (diag) {
          int key = n * 16 + l15, qq = w * 16 + g * 4 + i;
          if (key > qq) v = -1e30f;
        }
        ps[n][i] = v;
        mt[i] = fmaxf(mt[i], v);
      }
#pragma unroll
    for (int mm = 1; mm <= 8; mm <<= 1)
#pragma unroll
      for (int i = 0; i < 4; ++i) mt[i] = fmaxf(mt[i], __shfl_xor(mt[i], mm));
    float corr[4], rsum[4];
#pragma unroll
    for (int i = 0; i < 4; ++i) {
      float mn = fmaxf(m_i[i], mt[i]);
      corr[i] = __expf(m_i[i] - mn);
      m_i[i] = mn;
      rsum[i] = 0.f;
    }
#pragma unroll
    for (int n = 0; n < 4; ++n)
#pragma unroll
      for (int i = 0; i < 4; ++i) {
        float p = __expf(ps[n][i] - m_i[i]);
        ps[n][i] = p;
        rsum[i] += p;
      }
#pragma unroll
    for (int mm = 1; mm <= 8; mm <<= 1)
#pragma unroll
      for (int i = 0; i < 4; ++i) rsum[i] += __shfl_xor(rsum[i], mm);
#pragma unroll
    for (int i = 0; i < 4; ++i) l_i[i] = l_i[i] * corr[i] + rsum[i];
#pragma unroll
    for (int db = 0; db < 8; ++db)
#pragma unroll
      for (int i = 0; i < 4; ++i) acc[db][i] *= corr[i];
    // P -> LDS (per-wave)
#pragma unroll
    for (int n = 0; n < 4; ++n)
#pragma unroll
      for (int i = 0; i < 4; ++i) Plds[w][g * 4 + i][n * 16 + l15] = __float2half(ps[n][i]);

    // PV: out[16q x 128d] += P[16q x 64k] * V[64k x 128d]
#pragma unroll
    for (int ks = 0; ks < 2; ++ks) {
      f16x8 pa = *(const f16x8*)((const char*)&Plds[w][0][0] + l15 * 144 + ks * 64 + g * 16);
#pragma unroll
      for (int db = 0; db < 8; ++db) {
        int d = db * 16 + l15;
        int ss = (ks * 4 + g) ^ (d & 7);
        f16x8 vf = *(const f16x8*)(Vlds + d * 128 + ss * 16);
        acc[db] = mfma16(pa, vf, acc[db]);
      }
    }
  }

#pragma unroll
  for (int db = 0; db < 8; ++db)
#pragma unroll
    for (int i = 0; i < 4; ++i) {
      int row = q0 + w * 16 + g * 4 + i;
      Out[(size_t)row * 4096 + h * 128 + db * 16 + l15] = __float2half(acc[db][i] / l_i[i]);
    }
}

// ---------------- launch ----------------
extern "C" void kernel_launch(void* const* d_in, const int* in_sizes, int n_in,
                              void* d_out, int out_size, void* d_ws, size_t ws_size,
                              hipStream_t stream) {
  (void)in_sizes; (void)n_in; (void)out_size; (void)ws_size;
  const float* hs = (const float*)d_in[0];
  const int* pos = (const int*)d_in[2];
  const float* q_a_w = (const float*)d_in[3];
  const float* q_a_ln = (const float*)d_in[4];
  const float* q_b_w = (const float*)d_in[5];
  const float* kv_a_w = (const float*)d_in[6];
  const float* kv_a_ln = (const float*)d_in[7];
  const float* kv_b_w = (const float*)d_in[8];
  const float* o_w = (const float*)d_in[9];

  char* p = (char*)d_ws;
  auto alloc = [&](size_t sz) { char* r = p; p += (sz + 255) & ~(size_t)255; return r; };
  __half* hs_h = (__half*)alloc((size_t)2048 * 4096 * 2);   // later aliased as attn_out
  __half* w_qa = (__half*)alloc((size_t)1536 * 4096 * 2);
  __half* w_qb = (__half*)alloc((size_t)6144 * 1536 * 2);
  __half* w_kva = (__half*)alloc((size_t)640 * 4096 * 2);   // padded 576->640
  __half* w_kvb = (__half*)alloc((size_t)8192 * 512 * 2);
  float* qa_f = (float*)alloc((size_t)2048 * 1536 * 4);
  float* ckv_f = (float*)alloc((size_t)2048 * 576 * 4);
  __half* qa_r = (__half*)alloc((size_t)2048 * 1536 * 2);
  __half* kv_r = (__half*)alloc((size_t)2048 * 512 * 2);
  float2* cs_tab = (float2*)alloc((size_t)2048 * 32 * 8);
  __half* Qb = (__half*)alloc((size_t)32 * 2048 * 192 * 2);
  __half* Kb = (__half*)alloc((size_t)32 * 2048 * 192 * 2);
  __half* Vtb = (__half*)alloc((size_t)32 * 128 * 2048 * 2);
  __half* qpe = (__half*)alloc((size_t)2048 * 2048 * 2);
  __half* attn_h = hs_h;  // alias (hs_h dead after first two GEMMs)
  __half* w_o = Qb;       // alias (Q/K dead after attention; spans Qb+Kb, 33.5MB < 50MB)

  constexpr float QSCALE = 0.13086090981960297f;  // 192^-0.5 * (1+0.1*ln32)^2

  auto cvt = [&](const float* s, __half* d, size_t n) {
    int n4 = (int)(n / 4);
    int grid = (n4 + 255) / 256;
    if (grid > 2048) grid = 2048;
    cvt_kernel<<<grid, 256, 0, stream>>>(s, d, n4);
  };

  cvt(hs, hs_h, (size_t)2048 * 4096);
  cvt(q_a_w, w_qa, (size_t)1536 * 4096);
  hipMemsetAsync(w_kva + (size_t)576 * 4096, 0, (size_t)64 * 4096 * 2, stream);
  cvt(kv_a_w, w_kva, (size_t)576 * 4096);
  cvt(q_b_w, w_qb, (size_t)6144 * 1536);
  cvt(kv_b_w, w_kvb, (size_t)8192 * 512);
  rope_table_kernel<<<(2048 * 32) / 256, 256, 0, stream>>>(pos, cs_tab);

  gemm128<0><<<dim3(12, 16), 256, 0, stream>>>(hs_h, 4096, w_qa, 4096, 1536, qa_f, 1536,
                                               nullptr, nullptr, 1.f);
  gemm128<0><<<dim3(5, 16), 256, 0, stream>>>(hs_h, 4096, w_kva, 4096, 576, ckv_f, 576,
                                              nullptr, nullptr, 1.f);
  rms_kernel<1536><<<2048, 256, 0, stream>>>(qa_f, 1536, q_a_ln, qa_r, 1536);
  rms_kernel<512><<<2048, 256, 0, stream>>>(ckv_f, 576, kv_a_ln, kv_r, 512);
  rope_k_kernel<<<(2048 * 1024) / 256, 256, 0, stream>>>(ckv_f, cs_tab, Kb);
  gemm128<2><<<dim3(48, 16), 256, 0, stream>>>(qa_r, 1536, w_qb, 1536, 6144, nullptr, 0,
                                               Qb, qpe, QSCALE);
  rope_q_kernel<<<(2048 * 1024) / 256, 256, 0, stream>>>(qpe, cs_tab, Qb, QSCALE);
  gemm128<3><<<dim3(64, 16), 256, 0, stream>>>(kv_r, 512, w_kvb, 512, 8192, nullptr, 0,
                                               Kb, Vtb, 1.f);
  attn_kernel<<<dim3(32, 32), 256, 0, stream>>>(Qb, Kb, Vtb, attn_h);
  cvt(o_w, w_o, (size_t)4096 * 4096);
  gemm128<0><<<dim3(32, 16), 256, 0, stream>>>(attn_h, 4096, w_o, 4096, 4096, (float*)d_out,
                                               4096, nullptr, nullptr, 1.f);
}

// Round 4
// 548.697 us; speedup vs baseline: 1.1804x; 1.1804x over previous
//
#include <hip/hip_runtime.h>
#include <hip/hip_fp16.h>

typedef _Float16 f16x8 __attribute__((ext_vector_type(8)));
typedef float f32x4 __attribute__((ext_vector_type(4)));

#define DEV __device__ __forceinline__

typedef const __attribute__((address_space(1))) void gvoid_t;
typedef __attribute__((address_space(3))) void lvoid_t;

DEV void gload16(const void* g, void* l) {
  __builtin_amdgcn_global_load_lds((gvoid_t*)g, (lvoid_t*)l, 16, 0, 0);
}

DEV f32x4 mfma16(f16x8 a, f16x8 b, f32x4 c) {
  return __builtin_amdgcn_mfma_f32_16x16x32_f16(a, b, c, 0, 0, 0);
}

// ---------------- f32 -> f16 convert ----------------
__global__ __launch_bounds__(256) void cvt_kernel(const float* __restrict__ s,
                                                  __half* __restrict__ d, int n4) {
  int stride = gridDim.x * 256;
  for (int i = blockIdx.x * 256 + threadIdx.x; i < n4; i += stride) {
    float4 v = ((const float4*)s)[i];
    __align__(8) __half a[4] = {__float2half(v.x), __float2half(v.y),
                                __float2half(v.z), __float2half(v.w)};
    *((uint2*)(d + (size_t)i * 4)) = *((uint2*)a);
  }
}

// ---------------- RMSNorm (row-wise, f32 in -> f16 out) ----------------
template <int W>
__global__ __launch_bounds__(256) void rms_kernel(const float* __restrict__ x, int ldx,
                                                  const float* __restrict__ wgt,
                                                  __half* __restrict__ y, int ldy) {
  const int row = blockIdx.x, tid = threadIdx.x;
  const float4* xr = (const float4*)(x + (size_t)row * ldx);
  float4 v0 = make_float4(0.f, 0.f, 0.f, 0.f), v1 = v0;
  if (tid < W / 4) v0 = xr[tid];
  if (tid + 256 < W / 4) v1 = xr[tid + 256];
  float ss = v0.x * v0.x + v0.y * v0.y + v0.z * v0.z + v0.w * v0.w +
             v1.x * v1.x + v1.y * v1.y + v1.z * v1.z + v1.w * v1.w;
  for (int mm = 1; mm <= 32; mm <<= 1) ss += __shfl_xor(ss, mm);
  __shared__ float sred[4];
  if ((tid & 63) == 0) sred[tid >> 6] = ss;
  __syncthreads();
  float rs = 1.0f / sqrtf((sred[0] + sred[1] + sred[2] + sred[3]) * (1.0f / (float)W) + 1e-6f);
  __half* yr = y + (size_t)row * ldy;
  if (tid < W / 4) {
    int j = tid * 4;
    yr[j + 0] = __float2half(wgt[j + 0] * v0.x * rs);
    yr[j + 1] = __float2half(wgt[j + 1] * v0.y * rs);
    yr[j + 2] = __float2half(wgt[j + 2] * v0.z * rs);
    yr[j + 3] = __float2half(wgt[j + 3] * v0.w * rs);
  }
  if (tid + 256 < W / 4) {
    int j = (tid + 256) * 4;
    yr[j + 0] = __float2half(wgt[j + 0] * v1.x * rs);
    yr[j + 1] = __float2half(wgt[j + 1] * v1.y * rs);
    yr[j + 2] = __float2half(wgt[j + 2] * v1.z * rs);
    yr[j + 3] = __float2half(wgt[j + 3] * v1.w * rs);
  }
}

// ---------------- YaRN cos/sin table (double precision) ----------------
// dim=64, base=50000, factor=32, orig_max=4096 -> low=8, high=20
__global__ __launch_bounds__(256) void rope_table_kernel(const int* __restrict__ pos,
                                                         float2* __restrict__ cs) {
  int i = blockIdx.x * 256 + threadIdx.x;  // 2048*32
  int row = i >> 5, j = i & 31;
  double f = (double)j * (1.0 / 32.0);
  double fe = exp(-f * 10.81977828441028);  // BASE^-f
  double fi = fe * (1.0 / 32.0);
  double ramp = fmin(fmax(((double)j - 8.0) * (1.0 / 12.0), 0.0), 1.0);
  double inv = fi * ramp + fe * (1.0 - ramp);
  double ang = (double)pos[row] * inv;
  cs[i] = make_float2((float)cos(ang), (float)sin(ang));
}

// rope for q_pe: qpe [2048][32*64] f16 -> Q [h][row][128..191], scaled
__global__ __launch_bounds__(256) void rope_q_kernel(const __half* __restrict__ qpe,
                                                     const float2* __restrict__ cs,
                                                     __half* __restrict__ Qb, float qscale) {
  int i = blockIdx.x * 256 + threadIdx.x;  // 2048*32*32
  int row = i >> 10, rem = i & 1023, h = rem >> 5, j = rem & 31;
  float x0 = __half2float(qpe[(size_t)row * 2048 + h * 64 + 2 * j]);
  float x1 = __half2float(qpe[(size_t)row * 2048 + h * 64 + 2 * j + 1]);
  float2 c = cs[row * 32 + j];
  float o0 = (x0 * c.x - x1 * c.y) * qscale;
  float o1 = (x1 * c.x + x0 * c.y) * qscale;
  __half* dst = Qb + ((size_t)h * 2048 + row) * 192;
  dst[128 + j] = __float2half(o0);
  dst[160 + j] = __float2half(o1);
}

// rope for k_pe (f32 src rows [2048][ld], cols 0..63), broadcast to all 32 heads
__global__ __launch_bounds__(256) void rope_k_kernel(const float* __restrict__ kpe, int ld,
                                                     const float2* __restrict__ cs,
                                                     __half* __restrict__ Kb) {
  int i = blockIdx.x * 256 + threadIdx.x;  // 2048*32*32
  int row = i >> 10, rem = i & 1023, h = rem >> 5, j = rem & 31;
  float x0 = kpe[(size_t)row * ld + 2 * j];
  float x1 = kpe[(size_t)row * ld + 2 * j + 1];
  float2 c = cs[row * 32 + j];
  __half* dst = Kb + ((size_t)h * 2048 + row) * 192;
  dst[128 + j] = __float2half(x0 * c.x - x1 * c.y);
  dst[160 + j] = __float2half(x1 * c.x + x0 * c.y);
}

// ---------------- GEMM: C[M,N] = A[M,K](f16) x B[N,K](f16)^T ----------------
// 128x128 tile, BK=32, 4 waves 2x2, 16x16x32 MFMA, XCD-chunked block swizzle.
// EPI: 0=f32 store, 2=q_b split (Q nope *scale + qpe), 3=kv_b split (K nope + V^T)
template <int EPI>
__global__ __launch_bounds__(256) void gemm128(const __half* __restrict__ A, int lda,
                                               const __half* __restrict__ B, int K, int Ncols,
                                               float* __restrict__ Cf, int ldc,
                                               __half* __restrict__ O1, __half* __restrict__ O2,
                                               float qscale) {
  __shared__ __align__(16) char As[8192];
  __shared__ __align__(16) char Bs[8192];
  const int tid = threadIdx.x;
  const int lane = tid & 63, w = tid >> 6;
  const int l15 = lane & 15, g = lane >> 4;
  const int wr = w >> 1, wc = w & 1;
  // XCD-chunk swizzle (nwg % 8 == 0 for all launches)
  const int nwg = gridDim.x * gridDim.y;
  int wg = blockIdx.y * gridDim.x + blockIdx.x;
  wg = (wg & 7) * (nwg >> 3) + (wg >> 3);
  const int m0 = (wg / gridDim.x) * 128, n0 = (wg % gridDim.x) * 128;
  const int srow = lane >> 2, scol = (lane & 3) * 8;
  f32x4 acc[4][4] = {};

  for (int kt = 0; kt < K; kt += 32) {
    __syncthreads();
#pragma unroll
    for (int cc = 0; cc < 2; ++cc) {
      int c = 2 * w + cc;
      gload16(A + (size_t)(m0 + c * 16 + srow) * lda + kt + scol, As + c * 1024);
      gload16(B + (size_t)(n0 + c * 16 + srow) * K + kt + scol, Bs + c * 1024);
    }
    __syncthreads();
    f16x8 af[4], bf[4];
#pragma unroll
    for (int m = 0; m < 4; ++m)
      af[m] = *(const f16x8*)(As + (wr * 64 + m * 16 + l15) * 64 + g * 16);
#pragma unroll
    for (int n = 0; n < 4; ++n)
      bf[n] = *(const f16x8*)(Bs + (wc * 64 + n * 16 + l15) * 64 + g * 16);
#pragma unroll
    for (int m = 0; m < 4; ++m)
#pragma unroll
      for (int n = 0; n < 4; ++n) acc[m][n] = mfma16(af[m], bf[n], acc[m][n]);
  }

#pragma unroll
  for (int m = 0; m < 4; ++m)
#pragma unroll
    for (int n = 0; n < 4; ++n)
#pragma unroll
      for (int i = 0; i < 4; ++i) {
        int row = m0 + wr * 64 + m * 16 + g * 4 + i;
        int col = n0 + wc * 64 + n * 16 + l15;
        float v = acc[m][n][i];
        if (EPI == 0) {
          if (col < Ncols) Cf[(size_t)row * ldc + col] = v;
        } else if (EPI == 2) {
          int h = col / 192, d = col - h * 192;
          if (d < 128)
            O1[((size_t)h * 2048 + row) * 192 + d] = __float2half(v * qscale);
          else
            O2[(size_t)row * 2048 + h * 64 + (d - 128)] = __float2half(v);
        } else if (EPI == 3) {
          int h = col >> 8, d = col & 255;
          if (d < 128)
            O1[((size_t)h * 2048 + row) * 192 + d] = __float2half(v);
          else
            O2[((size_t)h * 128 + (d - 128)) * 2048 + row] = __float2half(v);
        }
      }
}

// ---------------- Flash attention ----------------
// grid (16 pairs, 32 heads); each block does q-tiles pr and 31-pr (33 KV-iters total,
// uniform). 4 waves; 16 q-rows/wave; KVB=64. XCD-chunked swizzle (4 heads/XCD).
// Q [h][2048][192] (pre-scaled), K [h][2048][192], Vt [h][128][2048], Out [2048][4096]
__global__ __launch_bounds__(256) void attn_kernel(const __half* __restrict__ Q,
                                                   const __half* __restrict__ K,
                                                   const __half* __restrict__ Vt,
                                                   __half* __restrict__ Out) {
  __shared__ __align__(16) char Klds[64 * 384];
  __shared__ __align__(16) char Vlds[128 * 128];
  __shared__ __align__(16) __half Plds[4][16][72];  // 144B row stride, cols 0..63 used
  int wg = blockIdx.y * gridDim.x + blockIdx.x;     // 512 blocks
  wg = (wg & 7) * 64 + (wg >> 3);
  const int pr = wg & 15, h = wg >> 4;
  const int tid = threadIdx.x, lane = tid & 63, w = tid >> 6;
  const int l15 = lane & 15, g = lane >> 4;

  const char* Kg = (const char*)(K + (size_t)h * 2048 * 192);
  const char* Vg = (const char*)(Vt + (size_t)h * 128 * 2048);

  for (int ht = 0; ht < 2; ++ht) {
    const int qt = ht ? (31 - pr) : pr;
    const int q0 = qt * 64;

    const __half* Qh = Q + ((size_t)h * 2048 + q0 + w * 16 + l15) * 192;
    f16x8 qf[6];
#pragma unroll
    for (int kc = 0; kc < 6; ++kc) qf[kc] = *(const f16x8*)(Qh + kc * 32 + g * 8);

    f32x4 acc[8] = {};
    float m_i[4], l_i[4];
#pragma unroll
    for (int i = 0; i < 4; ++i) { m_i[i] = -1e30f; l_i[i] = 0.f; }

    for (int kv0 = 0; kv0 <= q0; kv0 += 64) {
      __syncthreads();
      // stage K tile [64][192] f16, XOR-swizzled within rows (8-slot groups)
#pragma unroll
      for (int cc = 0; cc < 6; ++cc) {
        int c = w * 6 + cc;
        int L = c * 64 + lane;
        int row = (L * 2731) >> 16;  // L/24
        int slot = L - row * 24;
        int ss = (slot & ~7) | ((slot ^ row) & 7);
        gload16(Kg + (size_t)(kv0 + row) * 384 + ss * 16, Klds + c * 1024);
      }
      // stage V^T tile [128][64] f16, XOR-swizzled
#pragma unroll
      for (int cc = 0; cc < 4; ++cc) {
        int c = w * 4 + cc;
        int L = c * 64 + lane;
        int d = L >> 3, slot = L & 7;
        int ss = slot ^ (d & 7);
        gload16(Vg + ((size_t)d * 2048 + kv0) * 2 + ss * 16, Vlds + c * 1024);
      }
      __syncthreads();

      // scores: S[16q x 64k] per wave
      f32x4 s[4] = {};
#pragma unroll
      for (int kc = 0; kc < 6; ++kc) {
#pragma unroll
        for (int n = 0; n < 4; ++n) {
          int krow = n * 16 + l15;
          int slot = kc * 4 + g;
          int ss = (slot & ~7) | ((slot ^ krow) & 7);
          f16x8 kf = *(const f16x8*)(Klds + krow * 384 + ss * 16);
          s[n] = mfma16(qf[kc], kf, s[n]);
        }
      }

      const bool diag = (kv0 == q0);
      float ps[4][4];
      float mt[4] = {-1e30f, -1e30f, -1e30f, -1e30f};
#pragma unroll
      for (int n = 0; n < 4; ++n)
#pragma unroll
        for (int i = 0; i < 4; ++i) {
          float v = s[n][i];
          if (diag) {
            int key = n * 16 + l15, qq = w * 16 + g * 4 + i;
            if (key > qq) v = -1e30f;
          }
          ps[n][i] = v;
          mt[i] = fmaxf(mt[i], v);
        }
#pragma unroll
      for (int mm = 1; mm <= 8; mm <<= 1)
#pragma unroll
        for (int i = 0; i < 4; ++i) mt[i] = fmaxf(mt[i], __shfl_xor(mt[i], mm));
      float corr[4], rsum[4];
#pragma unroll
      for (int i = 0; i < 4; ++i) {
        float mn = fmaxf(m_i[i], mt[i]);
        corr[i] = __expf(m_i[i] - mn);
        m_i[i] = mn;
        rsum[i] = 0.f;
      }
#pragma unroll
      for (int n = 0; n < 4; ++n)
#pragma unroll
        for (int i = 0; i < 4; ++i) {
          float p = __expf(ps[n][i] - m_i[i]);
          ps[n][i] = p;
          rsum[i] += p;
        }
#pragma unroll
      for (int mm = 1; mm <= 8; mm <<= 1)
#pragma unroll
        for (int i = 0; i < 4; ++i) rsum[i] += __shfl_xor(rsum[i], mm);
#pragma unroll
      for (int i = 0; i < 4; ++i) l_i[i] = l_i[i] * corr[i] + rsum[i];
#pragma unroll
      for (int db = 0; db < 8; ++db)
#pragma unroll
        for (int i = 0; i < 4; ++i) acc[db][i] *= corr[i];
      // P -> LDS (per-wave)
#pragma unroll
      for (int n = 0; n < 4; ++n)
#pragma unroll
        for (int i = 0; i < 4; ++i) Plds[w][g * 4 + i][n * 16 + l15] = __float2half(ps[n][i]);

      // PV: out[16q x 128d] += P[16q x 64k] * V[64k x 128d]
#pragma unroll
      for (int ks = 0; ks < 2; ++ks) {
        f16x8 pa = *(const f16x8*)((const char*)&Plds[w][0][0] + l15 * 144 + ks * 64 + g * 16);
#pragma unroll
        for (int db = 0; db < 8; ++db) {
          int d = db * 16 + l15;
          int ss = (ks * 4 + g) ^ (d & 7);
          f16x8 vf = *(const f16x8*)(Vlds + d * 128 + ss * 16);
          acc[db] = mfma16(pa, vf, acc[db]);
        }
      }
    }

#pragma unroll
    for (int db = 0; db < 8; ++db)
#pragma unroll
      for (int i = 0; i < 4; ++i) {
        int row = q0 + w * 16 + g * 4 + i;
        Out[(size_t)row * 4096 + h * 128 + db * 16 + l15] = __float2half(acc[db][i] / l_i[i]);
      }
  }
}

// ---------------- launch ----------------
extern "C" void kernel_launch(void* const* d_in, const int* in_sizes, int n_in,
                              void* d_out, int out_size, void* d_ws, size_t ws_size,
                              hipStream_t stream) {
  (void)in_sizes; (void)n_in; (void)out_size; (void)ws_size;
  const float* hs = (const float*)d_in[0];
  const int* pos = (const int*)d_in[2];
  const float* q_a_w = (const float*)d_in[3];
  const float* q_a_ln = (const float*)d_in[4];
  const float* q_b_w = (const float*)d_in[5];
  const float* kv_a_w = (const float*)d_in[6];
  const float* kv_a_ln = (const float*)d_in[7];
  const float* kv_b_w = (const float*)d_in[8];
  const float* o_w = (const float*)d_in[9];

  char* p = (char*)d_ws;
  auto alloc = [&](size_t sz) { char* r = p; p += (sz + 255) & ~(size_t)255; return r; };
  __half* hs_h = (__half*)alloc((size_t)2048 * 4096 * 2);   // later aliased as attn_out
  __half* w_qab = (__half*)alloc((size_t)2176 * 4096 * 2);  // q_a rows 0..1535, kv_a 1536..2111, pad
  __half* w_qb = (__half*)alloc((size_t)6144 * 1536 * 2);
  __half* w_kvb = (__half*)alloc((size_t)8192 * 512 * 2);
  float* qab_f = (float*)alloc((size_t)2048 * 2112 * 4);    // [2048][2112]
  __half* qa_r = (__half*)alloc((size_t)2048 * 1536 * 2);
  __half* kv_r = (__half*)alloc((size_t)2048 * 512 * 2);
  float2* cs_tab = (float2*)alloc((size_t)2048 * 32 * 8);
  __half* Qb = (__half*)alloc((size_t)32 * 2048 * 192 * 2);
  __half* Kb = (__half*)alloc((size_t)32 * 2048 * 192 * 2);
  __half* Vtb = (__half*)alloc((size_t)32 * 128 * 2048 * 2);
  __half* qpe = (__half*)alloc((size_t)2048 * 2048 * 2);
  __half* attn_h = hs_h;  // alias (hs_h dead after A-GEMM)
  __half* w_o = Qb;       // alias (Q/K dead after attention; spans Qb+Kb, 33.5MB < 50MB)

  constexpr float QSCALE = 0.13086090981960297f;  // 192^-0.5 * (1+0.1*ln32)^2

  auto cvt = [&](const float* s, __half* d, size_t n) {
    int n4 = (int)(n / 4);
    int grid = (n4 + 255) / 256;
    if (grid > 2048) grid = 2048;
    cvt_kernel<<<grid, 256, 0, stream>>>(s, d, n4);
  };

  cvt(hs, hs_h, (size_t)2048 * 4096);
  cvt(q_a_w, w_qab, (size_t)1536 * 4096);
  cvt(kv_a_w, w_qab + (size_t)1536 * 4096, (size_t)576 * 4096);
  cvt(q_b_w, w_qb, (size_t)6144 * 1536);
  cvt(kv_b_w, w_kvb, (size_t)8192 * 512);
  rope_table_kernel<<<(2048 * 32) / 256, 256, 0, stream>>>(pos, cs_tab);

  // combined q_a + kv_a projection: [2048,4096] x [2112,4096]^T
  gemm128<0><<<dim3(17, 16), 256, 0, stream>>>(hs_h, 4096, w_qab, 4096, 2112, qab_f, 2112,
                                               nullptr, nullptr, 1.f);
  rms_kernel<1536><<<2048, 256, 0, stream>>>(qab_f, 2112, q_a_ln, qa_r, 1536);
  rms_kernel<512><<<2048, 256, 0, stream>>>(qab_f + 1536, 2112, kv_a_ln, kv_r, 512);
  rope_k_kernel<<<(2048 * 1024) / 256, 256, 0, stream>>>(qab_f + 2048, 2112, cs_tab, Kb);
  gemm128<2><<<dim3(48, 16), 256, 0, stream>>>(qa_r, 1536, w_qb, 1536, 6144, nullptr, 0,
                                               Qb, qpe, QSCALE);
  rope_q_kernel<<<(2048 * 1024) / 256, 256, 0, stream>>>(qpe, cs_tab, Qb, QSCALE);
  gemm128<3><<<dim3(64, 16), 256, 0, stream>>>(kv_r, 512, w_kvb, 512, 8192, nullptr, 0,
                                               Kb, Vtb, 1.f);
  attn_kernel<<<dim3(16, 32), 256, 0, stream>>>(Qb, Kb, Vtb, attn_h);
  cvt(o_w, w_o, (size_t)4096 * 4096);
  gemm128<0><<<dim3(32, 16), 256, 0, stream>>>(attn_h, 4096, w_o, 4096, 4096, (float*)d_out,
                                               4096, nullptr, nullptr, 1.f);
}

// Round 5
// 500.294 us; speedup vs baseline: 1.2946x; 1.0967x over previous
//
#include <hip/hip_runtime.h>
#include <hip/hip_fp16.h>

typedef _Float16 f16x8 __attribute__((ext_vector_type(8)));
typedef float f32x4 __attribute__((ext_vector_type(4)));

#define DEV __device__ __forceinline__

typedef const __attribute__((address_space(1))) void gvoid_t;
typedef __attribute__((address_space(3))) void lvoid_t;

DEV void gload16(const void* g, void* l) {
  __builtin_amdgcn_global_load_lds((gvoid_t*)g, (lvoid_t*)l, 16, 0, 0);
}

DEV f32x4 mfma16(f16x8 a, f16x8 b, f32x4 c) {
  return __builtin_amdgcn_mfma_f32_16x16x32_f16(a, b, c, 0, 0, 0);
}

// ---------------- f32 -> f16 convert ----------------
__global__ __launch_bounds__(256) void cvt_kernel(const float* __restrict__ s,
                                                  __half* __restrict__ d, int n4) {
  int stride = gridDim.x * 256;
  for (int i = blockIdx.x * 256 + threadIdx.x; i < n4; i += stride) {
    float4 v = ((const float4*)s)[i];
    __align__(8) __half a[4] = {__float2half(v.x), __float2half(v.y),
                                __float2half(v.z), __float2half(v.w)};
    *((uint2*)(d + (size_t)i * 4)) = *((uint2*)a);
  }
}

// ---------------- RMSNorm (row-wise, f32 in -> f16 out) ----------------
template <int W>
__global__ __launch_bounds__(256) void rms_kernel(const float* __restrict__ x, int ldx,
                                                  const float* __restrict__ wgt,
                                                  __half* __restrict__ y, int ldy) {
  const int row = blockIdx.x, tid = threadIdx.x;
  const float4* xr = (const float4*)(x + (size_t)row * ldx);
  float4 v0 = make_float4(0.f, 0.f, 0.f, 0.f), v1 = v0;
  if (tid < W / 4) v0 = xr[tid];
  if (tid + 256 < W / 4) v1 = xr[tid + 256];
  float ss = v0.x * v0.x + v0.y * v0.y + v0.z * v0.z + v0.w * v0.w +
             v1.x * v1.x + v1.y * v1.y + v1.z * v1.z + v1.w * v1.w;
  for (int mm = 1; mm <= 32; mm <<= 1) ss += __shfl_xor(ss, mm);
  __shared__ float sred[4];
  if ((tid & 63) == 0) sred[tid >> 6] = ss;
  __syncthreads();
  float rs = 1.0f / sqrtf((sred[0] + sred[1] + sred[2] + sred[3]) * (1.0f / (float)W) + 1e-6f);
  __half* yr = y + (size_t)row * ldy;
  if (tid < W / 4) {
    int j = tid * 4;
    yr[j + 0] = __float2half(wgt[j + 0] * v0.x * rs);
    yr[j + 1] = __float2half(wgt[j + 1] * v0.y * rs);
    yr[j + 2] = __float2half(wgt[j + 2] * v0.z * rs);
    yr[j + 3] = __float2half(wgt[j + 3] * v0.w * rs);
  }
  if (tid + 256 < W / 4) {
    int j = (tid + 256) * 4;
    yr[j + 0] = __float2half(wgt[j + 0] * v1.x * rs);
    yr[j + 1] = __float2half(wgt[j + 1] * v1.y * rs);
    yr[j + 2] = __float2half(wgt[j + 2] * v1.z * rs);
    yr[j + 3] = __float2half(wgt[j + 3] * v1.w * rs);
  }
}

// ---------------- YaRN cos/sin table (double precision) ----------------
// dim=64, base=50000, factor=32, orig_max=4096 -> low=8, high=20
__global__ __launch_bounds__(256) void rope_table_kernel(const int* __restrict__ pos,
                                                         float2* __restrict__ cs) {
  int i = blockIdx.x * 256 + threadIdx.x;  // 2048*32
  int row = i >> 5, j = i & 31;
  double f = (double)j * (1.0 / 32.0);
  double fe = exp(-f * 10.81977828441028);  // BASE^-f
  double fi = fe * (1.0 / 32.0);
  double ramp = fmin(fmax(((double)j - 8.0) * (1.0 / 12.0), 0.0), 1.0);
  double inv = fi * ramp + fe * (1.0 - ramp);
  double ang = (double)pos[row] * inv;
  cs[i] = make_float2((float)cos(ang), (float)sin(ang));
}

// rope for q_pe: qpe [2048][32*64] f16 -> Q [h][row][128..191], scaled
__global__ __launch_bounds__(256) void rope_q_kernel(const __half* __restrict__ qpe,
                                                     const float2* __restrict__ cs,
                                                     __half* __restrict__ Qb, float qscale) {
  int i = blockIdx.x * 256 + threadIdx.x;  // 2048*32*32
  int row = i >> 10, rem = i & 1023, h = rem >> 5, j = rem & 31;
  float x0 = __half2float(qpe[(size_t)row * 2048 + h * 64 + 2 * j]);
  float x1 = __half2float(qpe[(size_t)row * 2048 + h * 64 + 2 * j + 1]);
  float2 c = cs[row * 32 + j];
  float o0 = (x0 * c.x - x1 * c.y) * qscale;
  float o1 = (x1 * c.x + x0 * c.y) * qscale;
  __half* dst = Qb + ((size_t)h * 2048 + row) * 192;
  dst[128 + j] = __float2half(o0);
  dst[160 + j] = __float2half(o1);
}

// rope for k_pe (f32 src rows [2048][ld], cols 0..63), broadcast to all 32 heads
__global__ __launch_bounds__(256) void rope_k_kernel(const float* __restrict__ kpe, int ld,
                                                     const float2* __restrict__ cs,
                                                     __half* __restrict__ Kb) {
  int i = blockIdx.x * 256 + threadIdx.x;  // 2048*32*32
  int row = i >> 10, rem = i & 1023, h = rem >> 5, j = rem & 31;
  float x0 = kpe[(size_t)row * ld + 2 * j];
  float x1 = kpe[(size_t)row * ld + 2 * j + 1];
  float2 c = cs[row * 32 + j];
  __half* dst = Kb + ((size_t)h * 2048 + row) * 192;
  dst[128 + j] = __float2half(x0 * c.x - x1 * c.y);
  dst[160 + j] = __float2half(x1 * c.x + x0 * c.y);
}

// ---------------- GEMM: C[M,N] = A[M,K](f16) x B[N,K](f16)^T ----------------
// 128x128 tile, BK=32, 4 waves 2x2, 16x16x32 MFMA, XCD-chunked block swizzle.
// EPI: 0=f32 store, 2=q_b split (Q nope *scale + qpe), 3=kv_b split (K nope + V^T)
template <int EPI>
__global__ __launch_bounds__(256) void gemm128(const __half* __restrict__ A, int lda,
                                               const __half* __restrict__ B, int K, int Ncols,
                                               float* __restrict__ Cf, int ldc,
                                               __half* __restrict__ O1, __half* __restrict__ O2,
                                               float qscale) {
  __shared__ __align__(16) char As[8192];
  __shared__ __align__(16) char Bs[8192];
  const int tid = threadIdx.x;
  const int lane = tid & 63, w = tid >> 6;
  const int l15 = lane & 15, g = lane >> 4;
  const int wr = w >> 1, wc = w & 1;
  // XCD-chunk swizzle (nwg % 8 == 0 for all launches)
  const int nwg = gridDim.x * gridDim.y;
  int wg = blockIdx.y * gridDim.x + blockIdx.x;
  wg = (wg & 7) * (nwg >> 3) + (wg >> 3);
  const int m0 = (wg / gridDim.x) * 128, n0 = (wg % gridDim.x) * 128;
  const int srow = lane >> 2, scol = (lane & 3) * 8;
  f32x4 acc[4][4] = {};

  for (int kt = 0; kt < K; kt += 32) {
    __syncthreads();
#pragma unroll
    for (int cc = 0; cc < 2; ++cc) {
      int c = 2 * w + cc;
      gload16(A + (size_t)(m0 + c * 16 + srow) * lda + kt + scol, As + c * 1024);
      gload16(B + (size_t)(n0 + c * 16 + srow) * K + kt + scol, Bs + c * 1024);
    }
    __syncthreads();
    f16x8 af[4], bf[4];
#pragma unroll
    for (int m = 0; m < 4; ++m)
      af[m] = *(const f16x8*)(As + (wr * 64 + m * 16 + l15) * 64 + g * 16);
#pragma unroll
    for (int n = 0; n < 4; ++n)
      bf[n] = *(const f16x8*)(Bs + (wc * 64 + n * 16 + l15) * 64 + g * 16);
#pragma unroll
    for (int m = 0; m < 4; ++m)
#pragma unroll
      for (int n = 0; n < 4; ++n) acc[m][n] = mfma16(af[m], bf[n], acc[m][n]);
  }

#pragma unroll
  for (int m = 0; m < 4; ++m)
#pragma unroll
    for (int n = 0; n < 4; ++n)
#pragma unroll
      for (int i = 0; i < 4; ++i) {
        int row = m0 + wr * 64 + m * 16 + g * 4 + i;
        int col = n0 + wc * 64 + n * 16 + l15;
        float v = acc[m][n][i];
        if (EPI == 0) {
          if (col < Ncols) Cf[(size_t)row * ldc + col] = v;
        } else if (EPI == 2) {
          int h = col / 192, d = col - h * 192;
          if (d < 128)
            O1[((size_t)h * 2048 + row) * 192 + d] = __float2half(v * qscale);
          else
            O2[(size_t)row * 2048 + h * 64 + (d - 128)] = __float2half(v);
        } else if (EPI == 3) {
          int h = col >> 8, d = col & 255;
          if (d < 128)
            O1[((size_t)h * 2048 + row) * 192 + d] = __float2half(v);
          else
            O2[((size_t)h * 128 + (d - 128)) * 2048 + row] = __float2half(v);
        }
      }
}

// ---------------- Flash attention (2-phase pipelined) ----------------
// grid (16 pairs, 32 heads); each block does q-tiles pr and 31-pr (33 KV-iters total).
// 4 waves; 16 q-rows/wave; KVB=64. K double-buffered (2x24KB), V single (16KB).
// Per iter: issue V(t)+K(t+1) -> QK(t) -> softmax -> P -> sync -> PV(t) -> sync.
// Q [h][2048][192] (pre-scaled), K [h][2048][192], Vt [h][128][2048], Out [2048][4096]
__global__ __launch_bounds__(256) void attn_kernel(const __half* __restrict__ Q,
                                                   const __half* __restrict__ K,
                                                   const __half* __restrict__ Vt,
                                                   __half* __restrict__ Out) {
  __shared__ __align__(16) char Klds[2 * 64 * 384];  // 49152
  __shared__ __align__(16) char Vlds[128 * 128];     // 16384
  __shared__ __align__(16) __half Plds[4][16][72];   // 9216; total 74752 -> 2 blocks/CU
  int wg = blockIdx.y * gridDim.x + blockIdx.x;      // 512 blocks
  wg = (wg & 7) * 64 + (wg >> 3);
  const int pr = wg & 15, h = wg >> 4;
  const int tid = threadIdx.x, lane = tid & 63, w = tid >> 6;
  const int l15 = lane & 15, g = lane >> 4;

  const char* Kg = (const char*)(K + (size_t)h * 2048 * 192);
  const char* Vg = (const char*)(Vt + (size_t)h * 128 * 2048);

  // per-wave staging geometry (K: 6 chunks of 1KB; V: 4 chunks of 1KB)
  int kL[6], kRow[6], kSS[6];
#pragma unroll
  for (int cc = 0; cc < 6; ++cc) {
    int c = w * 6 + cc;
    int L = c * 64 + lane;
    int row = (L * 2731) >> 16;  // L/24
    int slot = L - row * 24;
    kL[cc] = c;
    kRow[cc] = row;
    kSS[cc] = (slot & ~7) | ((slot ^ row) & 7);
  }

  for (int ht = 0; ht < 2; ++ht) {
    const int qt = ht ? (31 - pr) : pr;
    const int q0 = qt * 64;
    const int nt = qt + 1;

    const __half* Qh = Q + ((size_t)h * 2048 + q0 + w * 16 + l15) * 192;
    f16x8 qf[6];
#pragma unroll
    for (int kc = 0; kc < 6; ++kc) qf[kc] = *(const f16x8*)(Qh + kc * 32 + g * 8);

    f32x4 acc[8] = {};
    float m_i[4], l_i[4];
#pragma unroll
    for (int i = 0; i < 4; ++i) { m_i[i] = -1e30f; l_i[i] = 0.f; }

    // prologue: stage K(0) into buffer 0
#pragma unroll
    for (int cc = 0; cc < 6; ++cc)
      gload16(Kg + (size_t)kRow[cc] * 384 + kSS[cc] * 16, Klds + kL[cc] * 1024);
    __syncthreads();

    for (int t = 0; t < nt; ++t) {
      const int kv0 = t * 64;
      const char* Kcur = Klds + (t & 1) * 24576;

      // issue V(t) stage [128][64] f16, XOR-swizzled
#pragma unroll
      for (int cc = 0; cc < 4; ++cc) {
        int c = w * 4 + cc;
        int L = c * 64 + lane;
        int d = L >> 3, slot = L & 7;
        int ss = slot ^ (d & 7);
        gload16(Vg + ((size_t)d * 2048 + kv0) * 2 + ss * 16, Vlds + c * 1024);
      }
      // issue K(t+1) stage into other buffer
      if (t + 1 < nt) {
        char* Knxt = Klds + ((t + 1) & 1) * 24576;
#pragma unroll
        for (int cc = 0; cc < 6; ++cc)
          gload16(Kg + (size_t)(kv0 + 64 + kRow[cc]) * 384 + kSS[cc] * 16,
                  Knxt + kL[cc] * 1024);
      }

      // QK(t): S[16q x 64k] per wave (K staged in prior iteration)
      f32x4 s[4] = {};
#pragma unroll
      for (int kc = 0; kc < 6; ++kc) {
#pragma unroll
        for (int n = 0; n < 4; ++n) {
          int krow = n * 16 + l15;
          int slot = kc * 4 + g;
          int ss = (slot & ~7) | ((slot ^ krow) & 7);
          f16x8 kf = *(const f16x8*)(Kcur + krow * 384 + ss * 16);
          s[n] = mfma16(qf[kc], kf, s[n]);
        }
      }

      const bool diag = (t == nt - 1);
      float ps[4][4];
      float mt[4] = {-1e30f, -1e30f, -1e30f, -1e30f};
#pragma unroll
      for (int n = 0; n < 4; ++n)
#pragma unroll
        for (int i = 0; i < 4; ++i) {
          float v = s[n][i];
          if (diag) {
            int key = n * 16 + l15, qq = w * 16 + g * 4 + i;
            if (key > qq) v = -1e30f;
          }
          ps[n][i] = v;
          mt[i] = fmaxf(mt[i], v);
        }
#pragma unroll
      for (int mm = 1; mm <= 8; mm <<= 1)
#pragma unroll
        for (int i = 0; i < 4; ++i) mt[i] = fmaxf(mt[i], __shfl_xor(mt[i], mm));
      float corr[4], rsum[4];
#pragma unroll
      for (int i = 0; i < 4; ++i) {
        float mn = fmaxf(m_i[i], mt[i]);
        corr[i] = __expf(m_i[i] - mn);
        m_i[i] = mn;
        rsum[i] = 0.f;
      }
#pragma unroll
      for (int n = 0; n < 4; ++n)
#pragma unroll
        for (int i = 0; i < 4; ++i) {
          float p = __expf(ps[n][i] - m_i[i]);
          ps[n][i] = p;
          rsum[i] += p;
        }
#pragma unroll
      for (int mm = 1; mm <= 8; mm <<= 1)
#pragma unroll
        for (int i = 0; i < 4; ++i) rsum[i] += __shfl_xor(rsum[i], mm);
#pragma unroll
      for (int i = 0; i < 4; ++i) l_i[i] = l_i[i] * corr[i] + rsum[i];
#pragma unroll
      for (int db = 0; db < 8; ++db)
#pragma unroll
        for (int i = 0; i < 4; ++i) acc[db][i] *= corr[i];
      // P -> LDS (per-wave, private tile)
#pragma unroll
      for (int n = 0; n < 4; ++n)
#pragma unroll
        for (int i = 0; i < 4; ++i) Plds[w][g * 4 + i][n * 16 + l15] = __float2half(ps[n][i]);

      __syncthreads();  // drains V(t) [+K(t+1)] stages; all waves' QK reads done

      // PV: out[16q x 128d] += P[16q x 64k] * V[64k x 128d]
#pragma unroll
      for (int ks = 0; ks < 2; ++ks) {
        f16x8 pa = *(const f16x8*)((const char*)&Plds[w][0][0] + l15 * 144 + ks * 64 + g * 16);
#pragma unroll
        for (int db = 0; db < 8; ++db) {
          int d = db * 16 + l15;
          int ss = (ks * 4 + g) ^ (d & 7);
          f16x8 vf = *(const f16x8*)(Vlds + d * 128 + ss * 16);
          acc[db] = mfma16(pa, vf, acc[db]);
        }
      }
      __syncthreads();  // protect V/K buffer overwrite in next iteration
    }

#pragma unroll
    for (int db = 0; db < 8; ++db)
#pragma unroll
      for (int i = 0; i < 4; ++i) {
        int row = q0 + w * 16 + g * 4 + i;
        Out[(size_t)row * 4096 + h * 128 + db * 16 + l15] = __float2half(acc[db][i] / l_i[i]);
      }
  }
}

// ---------------- launch ----------------
extern "C" void kernel_launch(void* const* d_in, const int* in_sizes, int n_in,
                              void* d_out, int out_size, void* d_ws, size_t ws_size,
                              hipStream_t stream) {
  (void)in_sizes; (void)n_in; (void)out_size; (void)ws_size;
  const float* hs = (const float*)d_in[0];
  const int* pos = (const int*)d_in[2];
  const float* q_a_w = (const float*)d_in[3];
  const float* q_a_ln = (const float*)d_in[4];
  const float* q_b_w = (const float*)d_in[5];
  const float* kv_a_w = (const float*)d_in[6];
  const float* kv_a_ln = (const float*)d_in[7];
  const float* kv_b_w = (const float*)d_in[8];
  const float* o_w = (const float*)d_in[9];

  char* p = (char*)d_ws;
  auto alloc = [&](size_t sz) { char* r = p; p += (sz + 255) & ~(size_t)255; return r; };
  __half* hs_h = (__half*)alloc((size_t)2048 * 4096 * 2);   // later aliased as attn_out
  __half* w_qab = (__half*)alloc((size_t)2176 * 4096 * 2);  // q_a rows 0..1535, kv_a 1536..2111, pad
  __half* w_qb = (__half*)alloc((size_t)6144 * 1536 * 2);
  __half* w_kvb = (__half*)alloc((size_t)8192 * 512 * 2);
  float* qab_f = (float*)alloc((size_t)2048 * 2112 * 4);    // [2048][2112]
  __half* qa_r = (__half*)alloc((size_t)2048 * 1536 * 2);
  __half* kv_r = (__half*)alloc((size_t)2048 * 512 * 2);
  float2* cs_tab = (float2*)alloc((size_t)2048 * 32 * 8);
  __half* Qb = (__half*)alloc((size_t)32 * 2048 * 192 * 2);
  __half* Kb = (__half*)alloc((size_t)32 * 2048 * 192 * 2);
  __half* Vtb = (__half*)alloc((size_t)32 * 128 * 2048 * 2);
  __half* qpe = (__half*)alloc((size_t)2048 * 2048 * 2);
  __half* attn_h = hs_h;  // alias (hs_h dead after A-GEMM)
  __half* w_o = Qb;       // alias (Q/K dead after attention; spans Qb+Kb, 33.5MB < 50MB)

  constexpr float QSCALE = 0.13086090981960297f;  // 192^-0.5 * (1+0.1*ln32)^2

  auto cvt = [&](const float* s, __half* d, size_t n) {
    int n4 = (int)(n / 4);
    int grid = (n4 + 255) / 256;
    if (grid > 2048) grid = 2048;
    cvt_kernel<<<grid, 256, 0, stream>>>(s, d, n4);
  };

  cvt(hs, hs_h, (size_t)2048 * 4096);
  cvt(q_a_w, w_qab, (size_t)1536 * 4096);
  cvt(kv_a_w, w_qab + (size_t)1536 * 4096, (size_t)576 * 4096);
  cvt(q_b_w, w_qb, (size_t)6144 * 1536);
  cvt(kv_b_w, w_kvb, (size_t)8192 * 512);
  rope_table_kernel<<<(2048 * 32) / 256, 256, 0, stream>>>(pos, cs_tab);

  // combined q_a + kv_a projection: [2048,4096] x [2112,4096]^T
  gemm128<0><<<dim3(17, 16), 256, 0, stream>>>(hs_h, 4096, w_qab, 4096, 2112, qab_f, 2112,
                                               nullptr, nullptr, 1.f);
  rms_kernel<1536><<<2048, 256, 0, stream>>>(qab_f, 2112, q_a_ln, qa_r, 1536);
  rms_kernel<512><<<2048, 256, 0, stream>>>(qab_f + 1536, 2112, kv_a_ln, kv_r, 512);
  rope_k_kernel<<<(2048 * 1024) / 256, 256, 0, stream>>>(qab_f + 2048, 2112, cs_tab, Kb);
  gemm128<2><<<dim3(48, 16), 256, 0, stream>>>(qa_r, 1536, w_qb, 1536, 6144, nullptr, 0,
                                               Qb, qpe, QSCALE);
  rope_q_kernel<<<(2048 * 1024) / 256, 256, 0, stream>>>(qpe, cs_tab, Qb, QSCALE);
  gemm128<3><<<dim3(64, 16), 256, 0, stream>>>(kv_r, 512, w_kvb, 512, 8192, nullptr, 0,
                                               Kb, Vtb, 1.f);
  attn_kernel<<<dim3(16, 32), 256, 0, stream>>>(Qb, Kb, Vtb, attn_h);
  cvt(o_w, w_o, (size_t)4096 * 4096);
  gemm128<0><<<dim3(32, 16), 256, 0, stream>>>(attn_h, 4096, w_o, 4096, 4096, (float*)d_out,
                                               4096, nullptr, nullptr, 1.f);
}

// Round 6
// 440.960 us; speedup vs baseline: 1.4688x; 1.1346x over previous
//
#include <hip/hip_runtime.h>
#include <hip/hip_fp16.h>

typedef _Float16 f16x8 __attribute__((ext_vector_type(8)));
typedef float f32x4 __attribute__((ext_vector_type(4)));

#define DEV __device__ __forceinline__

typedef const __attribute__((address_space(1))) void gvoid_t;
typedef __attribute__((address_space(3))) void lvoid_t;

DEV void gload16(const void* g, void* l) {
  __builtin_amdgcn_global_load_lds((gvoid_t*)g, (lvoid_t*)l, 16, 0, 0);
}

DEV f32x4 mfma16(f16x8 a, f16x8 b, f32x4 c) {
  return __builtin_amdgcn_mfma_f32_16x16x32_f16(a, b, c, 0, 0, 0);
}

// ---------------- f32 -> f16 convert ----------------
__global__ __launch_bounds__(256) void cvt_kernel(const float* __restrict__ s,
                                                  __half* __restrict__ d, int n4) {
  int stride = gridDim.x * 256;
  for (int i = blockIdx.x * 256 + threadIdx.x; i < n4; i += stride) {
    float4 v = ((const float4*)s)[i];
    __align__(8) __half a[4] = {__float2half(v.x), __float2half(v.y),
                                __float2half(v.z), __float2half(v.w)};
    *((uint2*)(d + (size_t)i * 4)) = *((uint2*)a);
  }
}

// merged cvt for hs + 4 weight matrices (segment sizes hardcoded, float4 units)
__global__ __launch_bounds__(256) void cvt5_kernel(const float* __restrict__ s0,
                                                   const float* __restrict__ s1,
                                                   const float* __restrict__ s2,
                                                   const float* __restrict__ s3,
                                                   const float* __restrict__ s4,
                                                   __half* __restrict__ d0, __half* __restrict__ d1,
                                                   __half* __restrict__ d2, __half* __restrict__ d3,
                                                   __half* __restrict__ d4) {
  const int c0 = 2097152, c1 = 3670016, c2 = 4259840, c3 = 6619136, c4 = 7667712;
  int stride = gridDim.x * 256;
  for (int i = blockIdx.x * 256 + threadIdx.x; i < c4; i += stride) {
    const float* s;
    __half* d;
    int j;
    if (i < c0) { s = s0; d = d0; j = i; }
    else if (i < c1) { s = s1; d = d1; j = i - c0; }
    else if (i < c2) { s = s2; d = d2; j = i - c1; }
    else if (i < c3) { s = s3; d = d3; j = i - c2; }
    else { s = s4; d = d4; j = i - c3; }
    float4 v = ((const float4*)s)[j];
    __align__(8) __half a[4] = {__float2half(v.x), __float2half(v.y),
                                __float2half(v.z), __float2half(v.w)};
    *((uint2*)(d + (size_t)j * 4)) = *((uint2*)a);
  }
}

// ---------------- RMSNorm (row-wise, f32 in -> f16 out) ----------------
template <int W>
__global__ __launch_bounds__(256) void rms_kernel(const float* __restrict__ x, int ldx,
                                                  const float* __restrict__ wgt,
                                                  __half* __restrict__ y, int ldy) {
  const int row = blockIdx.x, tid = threadIdx.x;
  const float4* xr = (const float4*)(x + (size_t)row * ldx);
  float4 v0 = make_float4(0.f, 0.f, 0.f, 0.f), v1 = v0;
  if (tid < W / 4) v0 = xr[tid];
  if (tid + 256 < W / 4) v1 = xr[tid + 256];
  float ss = v0.x * v0.x + v0.y * v0.y + v0.z * v0.z + v0.w * v0.w +
             v1.x * v1.x + v1.y * v1.y + v1.z * v1.z + v1.w * v1.w;
  for (int mm = 1; mm <= 32; mm <<= 1) ss += __shfl_xor(ss, mm);
  __shared__ float sred[4];
  if ((tid & 63) == 0) sred[tid >> 6] = ss;
  __syncthreads();
  float rs = 1.0f / sqrtf((sred[0] + sred[1] + sred[2] + sred[3]) * (1.0f / (float)W) + 1e-6f);
  __half* yr = y + (size_t)row * ldy;
  if (tid < W / 4) {
    int j = tid * 4;
    yr[j + 0] = __float2half(wgt[j + 0] * v0.x * rs);
    yr[j + 1] = __float2half(wgt[j + 1] * v0.y * rs);
    yr[j + 2] = __float2half(wgt[j + 2] * v0.z * rs);
    yr[j + 3] = __float2half(wgt[j + 3] * v0.w * rs);
  }
  if (tid + 256 < W / 4) {
    int j = (tid + 256) * 4;
    yr[j + 0] = __float2half(wgt[j + 0] * v1.x * rs);
    yr[j + 1] = __float2half(wgt[j + 1] * v1.y * rs);
    yr[j + 2] = __float2half(wgt[j + 2] * v1.z * rs);
    yr[j + 3] = __float2half(wgt[j + 3] * v1.w * rs);
  }
}

// ---------------- YaRN cos/sin table (double precision) ----------------
// dim=64, base=50000, factor=32, orig_max=4096 -> low=8, high=20
__global__ __launch_bounds__(256) void rope_table_kernel(const int* __restrict__ pos,
                                                         float2* __restrict__ cs) {
  int i = blockIdx.x * 256 + threadIdx.x;  // 2048*32
  int row = i >> 5, j = i & 31;
  double f = (double)j * (1.0 / 32.0);
  double fe = exp(-f * 10.81977828441028);  // BASE^-f
  double fi = fe * (1.0 / 32.0);
  double ramp = fmin(fmax(((double)j - 8.0) * (1.0 / 12.0), 0.0), 1.0);
  double inv = fi * ramp + fe * (1.0 - ramp);
  double ang = (double)pos[row] * inv;
  cs[i] = make_float2((float)cos(ang), (float)sin(ang));
}

// rope for q_pe: qpe [2048][32*64] f16 -> Q [h][row][128..191], scaled
__global__ __launch_bounds__(256) void rope_q_kernel(const __half* __restrict__ qpe,
                                                     const float2* __restrict__ cs,
                                                     __half* __restrict__ Qb, float qscale) {
  int i = blockIdx.x * 256 + threadIdx.x;  // 2048*32*32
  int row = i >> 10, rem = i & 1023, h = rem >> 5, j = rem & 31;
  float x0 = __half2float(qpe[(size_t)row * 2048 + h * 64 + 2 * j]);
  float x1 = __half2float(qpe[(size_t)row * 2048 + h * 64 + 2 * j + 1]);
  float2 c = cs[row * 32 + j];
  float o0 = (x0 * c.x - x1 * c.y) * qscale;
  float o1 = (x1 * c.x + x0 * c.y) * qscale;
  __half* dst = Qb + ((size_t)h * 2048 + row) * 192;
  dst[128 + j] = __float2half(o0);
  dst[160 + j] = __float2half(o1);
}

// rope for k_pe (f32 src rows [2048][ld], cols 0..63), broadcast to all 32 heads
__global__ __launch_bounds__(256) void rope_k_kernel(const float* __restrict__ kpe, int ld,
                                                     const float2* __restrict__ cs,
                                                     __half* __restrict__ Kb) {
  int i = blockIdx.x * 256 + threadIdx.x;  // 2048*32*32
  int row = i >> 10, rem = i & 1023, h = rem >> 5, j = rem & 31;
  float x0 = kpe[(size_t)row * ld + 2 * j];
  float x1 = kpe[(size_t)row * ld + 2 * j + 1];
  float2 c = cs[row * 32 + j];
  __half* dst = Kb + ((size_t)h * 2048 + row) * 192;
  dst[128 + j] = __float2half(x0 * c.x - x1 * c.y);
  dst[160 + j] = __float2half(x1 * c.x + x0 * c.y);
}

// ---------------- GEMM: C[M,N] = A[M,K](f16) x B[N,K](f16)^T ----------------
// 128x128 tile, BK=64, 4 waves 2x2, double-buffered LDS (2x32KB), 2-phase
// prefetch (stage t+1 || compute t, one barrier/iter), XOR bank swizzle.
// EPI: 0=f32 store, 2=q_b split (Q nope *scale + qpe), 3=kv_b split (K nope + V^T)
template <int EPI>
__global__ __launch_bounds__(256) void gemm128(const __half* __restrict__ A, int lda,
                                               const __half* __restrict__ B, int K, int Ncols,
                                               float* __restrict__ Cf, int ldc,
                                               __half* __restrict__ O1, __half* __restrict__ O2,
                                               float qscale) {
  __shared__ __align__(16) char As[32768];  // 2 x [128 rows][128 B]
  __shared__ __align__(16) char Bs[32768];
  const int tid = threadIdx.x;
  const int lane = tid & 63, w = tid >> 6;
  const int l15 = lane & 15, g = lane >> 4;
  const int wr = w >> 1, wc = w & 1;
  // XCD-chunk swizzle (nwg % 8 == 0 for all launches)
  const int nwg = gridDim.x * gridDim.y;
  int wg = blockIdx.y * gridDim.x + blockIdx.x;
  wg = (wg & 7) * (nwg >> 3) + (wg >> 3);
  const int m0 = (wg / gridDim.x) * 128, n0 = (wg % gridDim.x) * 128;
  // staging geometry: 16 chunks of 1KB each (8 rows x 128B); wave w -> chunks 4w..4w+3
  const int srow = lane >> 3;                 // row within chunk
  const int scol = ((lane & 7) ^ srow) * 8;   // pre-swizzled source col (halves)
  f32x4 acc[4][4] = {};
  const int nt = K >> 6;

  auto stage = [&](int t, int buf) {
    const __half* Ab = A + t * 64 + scol;
    const __half* Bb = B + t * 64 + scol;
#pragma unroll
    for (int cc = 0; cc < 4; ++cc) {
      int ch = w * 4 + cc;
      gload16(Ab + (size_t)(m0 + ch * 8 + srow) * lda, As + buf * 16384 + ch * 1024);
      gload16(Bb + (size_t)(n0 + ch * 8 + srow) * K, Bs + buf * 16384 + ch * 1024);
    }
  };

  stage(0, 0);
  __syncthreads();

  for (int t = 0; t < nt; ++t) {
    const int buf = t & 1;
    if (t + 1 < nt) stage(t + 1, buf ^ 1);
    const char* Ab = As + buf * 16384;
    const char* Bb = Bs + buf * 16384;
#pragma unroll
    for (int kk = 0; kk < 2; ++kk) {
      f16x8 af[4], bf[4];
#pragma unroll
      for (int m = 0; m < 4; ++m) {
        int r = wr * 64 + m * 16 + l15;
        af[m] = *(const f16x8*)(Ab + r * 128 + (((kk << 2) | g) ^ (r & 7)) * 16);
      }
#pragma unroll
      for (int n = 0; n < 4; ++n) {
        int r = wc * 64 + n * 16 + l15;
        bf[n] = *(const f16x8*)(Bb + r * 128 + (((kk << 2) | g) ^ (r & 7)) * 16);
      }
#pragma unroll
      for (int m = 0; m < 4; ++m)
#pragma unroll
        for (int n = 0; n < 4; ++n) acc[m][n] = mfma16(af[m], bf[n], acc[m][n]);
    }
    __syncthreads();  // drains stage(t+1); separates reads of buf from overwrite
  }

#pragma unroll
  for (int m = 0; m < 4; ++m)
#pragma unroll
    for (int n = 0; n < 4; ++n)
#pragma unroll
      for (int i = 0; i < 4; ++i) {
        int row = m0 + wr * 64 + m * 16 + g * 4 + i;
        int col = n0 + wc * 64 + n * 16 + l15;
        float v = acc[m][n][i];
        if (EPI == 0) {
          if (col < Ncols) Cf[(size_t)row * ldc + col] = v;
        } else if (EPI == 2) {
          int h = col / 192, d = col - h * 192;
          if (d < 128)
            O1[((size_t)h * 2048 + row) * 192 + d] = __float2half(v * qscale);
          else
            O2[(size_t)row * 2048 + h * 64 + (d - 128)] = __float2half(v);
        } else if (EPI == 3) {
          int h = col >> 8, d = col & 255;
          if (d < 128)
            O1[((size_t)h * 2048 + row) * 192 + d] = __float2half(v);
          else
            O2[((size_t)h * 128 + (d - 128)) * 2048 + row] = __float2half(v);
        }
      }
}

// ---------------- Flash attention (2-phase pipelined) ----------------
// grid (16 pairs, 32 heads); each block does q-tiles pr and 31-pr (33 KV-iters total).
// 4 waves; 16 q-rows/wave; KVB=64. K double-buffered (2x24KB), V single (16KB).
// Per iter: issue V(t)+K(t+1) -> QK(t) -> softmax -> P -> sync -> PV(t) -> sync.
// Q [h][2048][192] (pre-scaled), K [h][2048][192], Vt [h][128][2048], Out [2048][4096]
__global__ __launch_bounds__(256) void attn_kernel(const __half* __restrict__ Q,
                                                   const __half* __restrict__ K,
                                                   const __half* __restrict__ Vt,
                                                   __half* __restrict__ Out) {
  __shared__ __align__(16) char Klds[2 * 64 * 384];  // 49152
  __shared__ __align__(16) char Vlds[128 * 128];     // 16384
  __shared__ __align__(16) __half Plds[4][16][72];   // 9216; total 74752 -> 2 blocks/CU
  int wg = blockIdx.y * gridDim.x + blockIdx.x;      // 512 blocks
  wg = (wg & 7) * 64 + (wg >> 3);
  const int pr = wg & 15, h = wg >> 4;
  const int tid = threadIdx.x, lane = tid & 63, w = tid >> 6;
  const int l15 = lane & 15, g = lane >> 4;

  const char* Kg = (const char*)(K + (size_t)h * 2048 * 192);
  const char* Vg = (const char*)(Vt + (size_t)h * 128 * 2048);

  // per-wave staging geometry (K: 6 chunks of 1KB; V: 4 chunks of 1KB)
  int kL[6], kRow[6], kSS[6];
#pragma unroll
  for (int cc = 0; cc < 6; ++cc) {
    int c = w * 6 + cc;
    int L = c * 64 + lane;
    int row = (L * 2731) >> 16;  // L/24
    int slot = L - row * 24;
    kL[cc] = c;
    kRow[cc] = row;
    kSS[cc] = (slot & ~7) | ((slot ^ row) & 7);
  }

  for (int ht = 0; ht < 2; ++ht) {
    const int qt = ht ? (31 - pr) : pr;
    const int q0 = qt * 64;
    const int nt = qt + 1;

    const __half* Qh = Q + ((size_t)h * 2048 + q0 + w * 16 + l15) * 192;
    f16x8 qf[6];
#pragma unroll
    for (int kc = 0; kc < 6; ++kc) qf[kc] = *(const f16x8*)(Qh + kc * 32 + g * 8);

    f32x4 acc[8] = {};
    float m_i[4], l_i[4];
#pragma unroll
    for (int i = 0; i < 4; ++i) { m_i[i] = -1e30f; l_i[i] = 0.f; }

    // prologue: stage K(0) into buffer 0
#pragma unroll
    for (int cc = 0; cc < 6; ++cc)
      gload16(Kg + (size_t)kRow[cc] * 384 + kSS[cc] * 16, Klds + kL[cc] * 1024);
    __syncthreads();

    for (int t = 0; t < nt; ++t) {
      const int kv0 = t * 64;
      const char* Kcur = Klds + (t & 1) * 24576;

      // issue V(t) stage [128][64] f16, XOR-swizzled
#pragma unroll
      for (int cc = 0; cc < 4; ++cc) {
        int c = w * 4 + cc;
        int L = c * 64 + lane;
        int d = L >> 3, slot = L & 7;
        int ss = slot ^ (d & 7);
        gload16(Vg + ((size_t)d * 2048 + kv0) * 2 + ss * 16, Vlds + c * 1024);
      }
      // issue K(t+1) stage into other buffer
      if (t + 1 < nt) {
        char* Knxt = Klds + ((t + 1) & 1) * 24576;
#pragma unroll
        for (int cc = 0; cc < 6; ++cc)
          gload16(Kg + (size_t)(kv0 + 64 + kRow[cc]) * 384 + kSS[cc] * 16,
                  Knxt + kL[cc] * 1024);
      }

      // QK(t): S[16q x 64k] per wave (K staged in prior iteration)
      f32x4 s[4] = {};
      __builtin_amdgcn_s_setprio(1);
#pragma unroll
      for (int kc = 0; kc < 6; ++kc) {
#pragma unroll
        for (int n = 0; n < 4; ++n) {
          int krow = n * 16 + l15;
          int slot = kc * 4 + g;
          int ss = (slot & ~7) | ((slot ^ krow) & 7);
          f16x8 kf = *(const f16x8*)(Kcur + krow * 384 + ss * 16);
          s[n] = mfma16(qf[kc], kf, s[n]);
        }
      }
      __builtin_amdgcn_s_setprio(0);

      const bool diag = (t == nt - 1);
      float ps[4][4];
      float mt[4] = {-1e30f, -1e30f, -1e30f, -1e30f};
#pragma unroll
      for (int n = 0; n < 4; ++n)
#pragma unroll
        for (int i = 0; i < 4; ++i) {
          float v = s[n][i];
          if (diag) {
            int key = n * 16 + l15, qq = w * 16 + g * 4 + i;
            if (key > qq) v = -1e30f;
          }
          ps[n][i] = v;
          mt[i] = fmaxf(mt[i], v);
        }
#pragma unroll
      for (int mm = 1; mm <= 8; mm <<= 1)
#pragma unroll
        for (int i = 0; i < 4; ++i) mt[i] = fmaxf(mt[i], __shfl_xor(mt[i], mm));
      float corr[4], rsum[4];
#pragma unroll
      for (int i = 0; i < 4; ++i) {
        float mn = fmaxf(m_i[i], mt[i]);
        corr[i] = __expf(m_i[i] - mn);
        m_i[i] = mn;
        rsum[i] = 0.f;
      }
#pragma unroll
      for (int n = 0; n < 4; ++n)
#pragma unroll
        for (int i = 0; i < 4; ++i) {
          float p = __expf(ps[n][i] - m_i[i]);
          ps[n][i] = p;
          rsum[i] += p;
        }
#pragma unroll
      for (int mm = 1; mm <= 8; mm <<= 1)
#pragma unroll
        for (int i = 0; i < 4; ++i) rsum[i] += __shfl_xor(rsum[i], mm);
#pragma unroll
      for (int i = 0; i < 4; ++i) l_i[i] = l_i[i] * corr[i] + rsum[i];
#pragma unroll
      for (int db = 0; db < 8; ++db)
#pragma unroll
        for (int i = 0; i < 4; ++i) acc[db][i] *= corr[i];
      // P -> LDS (per-wave, private tile)
#pragma unroll
      for (int n = 0; n < 4; ++n)
#pragma unroll
        for (int i = 0; i < 4; ++i) Plds[w][g * 4 + i][n * 16 + l15] = __float2half(ps[n][i]);

      __syncthreads();  // drains V(t) [+K(t+1)] stages; all waves' QK reads done

      // PV: out[16q x 128d] += P[16q x 64k] * V[64k x 128d]
      __builtin_amdgcn_s_setprio(1);
#pragma unroll
      for (int ks = 0; ks < 2; ++ks) {
        f16x8 pa = *(const f16x8*)((const char*)&Plds[w][0][0] + l15 * 144 + ks * 64 + g * 16);
#pragma unroll
        for (int db = 0; db < 8; ++db) {
          int d = db * 16 + l15;
          int ss = (ks * 4 + g) ^ (d & 7);
          f16x8 vf = *(const f16x8*)(Vlds + d * 128 + ss * 16);
          acc[db] = mfma16(pa, vf, acc[db]);
        }
      }
      __builtin_amdgcn_s_setprio(0);
      __syncthreads();  // protect V/K buffer overwrite in next iteration
    }

#pragma unroll
    for (int db = 0; db < 8; ++db)
#pragma unroll
      for (int i = 0; i < 4; ++i) {
        int row = q0 + w * 16 + g * 4 + i;
        Out[(size_t)row * 4096 + h * 128 + db * 16 + l15] = __float2half(acc[db][i] / l_i[i]);
      }
  }
}

// ---------------- launch ----------------
extern "C" void kernel_launch(void* const* d_in, const int* in_sizes, int n_in,
                              void* d_out, int out_size, void* d_ws, size_t ws_size,
                              hipStream_t stream) {
  (void)in_sizes; (void)n_in; (void)out_size; (void)ws_size;
  const float* hs = (const float*)d_in[0];
  const int* pos = (const int*)d_in[2];
  const float* q_a_w = (const float*)d_in[3];
  const float* q_a_ln = (const float*)d_in[4];
  const float* q_b_w = (const float*)d_in[5];
  const float* kv_a_w = (const float*)d_in[6];
  const float* kv_a_ln = (const float*)d_in[7];
  const float* kv_b_w = (const float*)d_in[8];
  const float* o_w = (const float*)d_in[9];

  char* p = (char*)d_ws;
  auto alloc = [&](size_t sz) { char* r = p; p += (sz + 255) & ~(size_t)255; return r; };
  __half* hs_h = (__half*)alloc((size_t)2048 * 4096 * 2);   // later aliased as attn_out
  __half* w_qab = (__half*)alloc((size_t)2176 * 4096 * 2);  // q_a rows 0..1535, kv_a 1536..2111, pad
  __half* w_qb = (__half*)alloc((size_t)6144 * 1536 * 2);
  __half* w_kvb = (__half*)alloc((size_t)8192 * 512 * 2);
  float* qab_f = (float*)alloc((size_t)2048 * 2112 * 4);    // [2048][2112]
  __half* qa_r = (__half*)alloc((size_t)2048 * 1536 * 2);
  __half* kv_r = (__half*)alloc((size_t)2048 * 512 * 2);
  float2* cs_tab = (float2*)alloc((size_t)2048 * 32 * 8);
  __half* Qb = (__half*)alloc((size_t)32 * 2048 * 192 * 2);
  __half* Kb = (__half*)alloc((size_t)32 * 2048 * 192 * 2);
  __half* Vtb = (__half*)alloc((size_t)32 * 128 * 2048 * 2);
  __half* qpe = (__half*)alloc((size_t)2048 * 2048 * 2);
  __half* attn_h = hs_h;  // alias (hs_h dead after A-GEMM)
  __half* w_o = Qb;       // alias (Q/K dead after attention; spans Qb+Kb, 33.5MB < 50MB)

  constexpr float QSCALE = 0.13086090981960297f;  // 192^-0.5 * (1+0.1*ln32)^2

  // merged f32->f16: hs, q_a_w, kv_a_w, q_b_w, kv_b_w
  cvt5_kernel<<<2048, 256, 0, stream>>>(hs, q_a_w, kv_a_w, q_b_w, kv_b_w,
                                        hs_h, w_qab, w_qab + (size_t)1536 * 4096,
                                        w_qb, w_kvb);
  rope_table_kernel<<<(2048 * 32) / 256, 256, 0, stream>>>(pos, cs_tab);

  // combined q_a + kv_a projection: [2048,4096] x [2112,4096]^T
  gemm128<0><<<dim3(17, 16), 256, 0, stream>>>(hs_h, 4096, w_qab, 4096, 2112, qab_f, 2112,
                                               nullptr, nullptr, 1.f);
  rms_kernel<1536><<<2048, 256, 0, stream>>>(qab_f, 2112, q_a_ln, qa_r, 1536);
  rms_kernel<512><<<2048, 256, 0, stream>>>(qab_f + 1536, 2112, kv_a_ln, kv_r, 512);
  rope_k_kernel<<<(2048 * 1024) / 256, 256, 0, stream>>>(qab_f + 2048, 2112, cs_tab, Kb);
  gemm128<2><<<dim3(48, 16), 256, 0, stream>>>(qa_r, 1536, w_qb, 1536, 6144, nullptr, 0,
                                               Qb, qpe, QSCALE);
  rope_q_kernel<<<(2048 * 1024) / 256, 256, 0, stream>>>(qpe, cs_tab, Qb, QSCALE);
  gemm128<3><<<dim3(64, 16), 256, 0, stream>>>(kv_r, 512, w_kvb, 512, 8192, nullptr, 0,
                                               Kb, Vtb, 1.f);
  attn_kernel<<<dim3(16, 32), 256, 0, stream>>>(Qb, Kb, Vtb, attn_h);
  cvt_kernel<<<2048, 256, 0, stream>>>(o_w, w_o, (int)((size_t)4096 * 4096 / 4));
  gemm128<0><<<dim3(32, 16), 256, 0, stream>>>(attn_h, 4096, w_o, 4096, 4096, (float*)d_out,
                                               4096, nullptr, nullptr, 1.f);
}

// Round 7
// 421.057 us; speedup vs baseline: 1.5382x; 1.0473x over previous
//
#include <hip/hip_runtime.h>
#include <hip/hip_fp16.h>

typedef _Float16 f16x8 __attribute__((ext_vector_type(8)));
typedef float f32x4 __attribute__((ext_vector_type(4)));

#define DEV __device__ __forceinline__

typedef const __attribute__((address_space(1))) void gvoid_t;
typedef __attribute__((address_space(3))) void lvoid_t;

DEV void gload16(const void* g, void* l) {
  __builtin_amdgcn_global_load_lds((gvoid_t*)g, (lvoid_t*)l, 16, 0, 0);
}

DEV f32x4 mfma16(f16x8 a, f16x8 b, f32x4 c) {
  return __builtin_amdgcn_mfma_f32_16x16x32_f16(a, b, c, 0, 0, 0);
}

// ---------------- f32 -> f16 convert ----------------
__global__ __launch_bounds__(256) void cvt_kernel(const float* __restrict__ s,
                                                  __half* __restrict__ d, int n4) {
  int stride = gridDim.x * 256;
  for (int i = blockIdx.x * 256 + threadIdx.x; i < n4; i += stride) {
    float4 v = ((const float4*)s)[i];
    __align__(8) __half a[4] = {__float2half(v.x), __float2half(v.y),
                                __float2half(v.z), __float2half(v.w)};
    *((uint2*)(d + (size_t)i * 4)) = *((uint2*)a);
  }
}

// merged cvt for hs + 4 weight matrices (segment sizes hardcoded, float4 units)
__global__ __launch_bounds__(256) void cvt5_kernel(const float* __restrict__ s0,
                                                   const float* __restrict__ s1,
                                                   const float* __restrict__ s2,
                                                   const float* __restrict__ s3,
                                                   const float* __restrict__ s4,
                                                   __half* __restrict__ d0, __half* __restrict__ d1,
                                                   __half* __restrict__ d2, __half* __restrict__ d3,
                                                   __half* __restrict__ d4) {
  const int c0 = 2097152, c1 = 3670016, c2 = 4259840, c3 = 6619136, c4 = 7667712;
  int stride = gridDim.x * 256;
  for (int i = blockIdx.x * 256 + threadIdx.x; i < c4; i += stride) {
    const float* s;
    __half* d;
    int j;
    if (i < c0) { s = s0; d = d0; j = i; }
    else if (i < c1) { s = s1; d = d1; j = i - c0; }
    else if (i < c2) { s = s2; d = d2; j = i - c1; }
    else if (i < c3) { s = s3; d = d3; j = i - c2; }
    else { s = s4; d = d4; j = i - c3; }
    float4 v = ((const float4*)s)[j];
    __align__(8) __half a[4] = {__float2half(v.x), __float2half(v.y),
                                __float2half(v.z), __float2half(v.w)};
    *((uint2*)(d + (size_t)j * 4)) = *((uint2*)a);
  }
}

// ---------------- fused RMSNorm(q) + RMSNorm(kv) + k_pe RoPE ----------------
// qab row layout: [0..1535]=q_a, [1536..2047]=kv_a comp, [2048..2111]=k_pe
__global__ __launch_bounds__(256) void norm_rope_kernel(const float* __restrict__ qab,
                                                        const float* __restrict__ q_ln,
                                                        const float* __restrict__ kv_ln,
                                                        const float2* __restrict__ cs,
                                                        __half* __restrict__ qa_r,
                                                        __half* __restrict__ kv_r,
                                                        __half* __restrict__ Kb) {
  const int row = blockIdx.x, tid = threadIdx.x;
  const float* xr = qab + (size_t)row * 2112;
  float4 a0 = ((const float4*)xr)[tid];  // elems 0..1023
  float4 a1 = make_float4(0.f, 0.f, 0.f, 0.f);
  float4 b0 = make_float4(0.f, 0.f, 0.f, 0.f);
  if (tid < 128) {
    a1 = ((const float4*)xr)[256 + tid];        // 1024..1535
    b0 = ((const float4*)(xr + 1536))[tid];     // kv 0..511
  }
  float sq = a0.x * a0.x + a0.y * a0.y + a0.z * a0.z + a0.w * a0.w +
             a1.x * a1.x + a1.y * a1.y + a1.z * a1.z + a1.w * a1.w;
  float sk = b0.x * b0.x + b0.y * b0.y + b0.z * b0.z + b0.w * b0.w;
  for (int mm = 1; mm <= 32; mm <<= 1) {
    sq += __shfl_xor(sq, mm);
    sk += __shfl_xor(sk, mm);
  }
  __shared__ float r1[4], r2[4];
  __shared__ __half ro[64];
  if ((tid & 63) == 0) { r1[tid >> 6] = sq; r2[tid >> 6] = sk; }
  if (tid < 32) {
    float x0 = xr[2048 + 2 * tid], x1 = xr[2048 + 2 * tid + 1];
    float2 c = cs[row * 32 + tid];
    ro[tid] = __float2half(x0 * c.x - x1 * c.y);
    ro[32 + tid] = __float2half(x1 * c.x + x0 * c.y);
  }
  __syncthreads();
  float rsq = rsqrtf((r1[0] + r1[1] + r1[2] + r1[3]) * (1.f / 1536.f) + 1e-6f);
  float rsk = rsqrtf((r2[0] + r2[1] + r2[2] + r2[3]) * (1.f / 512.f) + 1e-6f);
  __half* yq = qa_r + (size_t)row * 1536;
  {
    int j = tid * 4;
    yq[j + 0] = __float2half(q_ln[j + 0] * a0.x * rsq);
    yq[j + 1] = __float2half(q_ln[j + 1] * a0.y * rsq);
    yq[j + 2] = __float2half(q_ln[j + 2] * a0.z * rsq);
    yq[j + 3] = __float2half(q_ln[j + 3] * a0.w * rsq);
  }
  if (tid < 128) {
    int j = 1024 + tid * 4;
    yq[j + 0] = __float2half(q_ln[j + 0] * a1.x * rsq);
    yq[j + 1] = __float2half(q_ln[j + 1] * a1.y * rsq);
    yq[j + 2] = __float2half(q_ln[j + 2] * a1.z * rsq);
    yq[j + 3] = __float2half(q_ln[j + 3] * a1.w * rsq);
    __half* yk = kv_r + (size_t)row * 512;
    int jk = tid * 4;
    yk[jk + 0] = __float2half(kv_ln[jk + 0] * b0.x * rsk);
    yk[jk + 1] = __float2half(kv_ln[jk + 1] * b0.y * rsk);
    yk[jk + 2] = __float2half(kv_ln[jk + 2] * b0.z * rsk);
    yk[jk + 3] = __float2half(kv_ln[jk + 3] * b0.w * rsk);
  }
#pragma unroll
  for (int it = 0; it < 8; ++it) {
    int i = it * 256 + tid;  // 0..2047
    int hh = i >> 6, d = i & 63;
    Kb[((size_t)hh * 2048 + row) * 192 + 128 + d] = ro[d];
  }
}

// ---------------- YaRN cos/sin table (double precision) ----------------
__global__ __launch_bounds__(256) void rope_table_kernel(const int* __restrict__ pos,
                                                         float2* __restrict__ cs) {
  int i = blockIdx.x * 256 + threadIdx.x;  // 2048*32
  int row = i >> 5, j = i & 31;
  double f = (double)j * (1.0 / 32.0);
  double fe = exp(-f * 10.81977828441028);  // BASE^-f
  double fi = fe * (1.0 / 32.0);
  double ramp = fmin(fmax(((double)j - 8.0) * (1.0 / 12.0), 0.0), 1.0);
  double inv = fi * ramp + fe * (1.0 - ramp);
  double ang = (double)pos[row] * inv;
  cs[i] = make_float2((float)cos(ang), (float)sin(ang));
}

// rope for q_pe: qpe [2048][32*64] f16 -> Q [h][row][128..191], scaled
__global__ __launch_bounds__(256) void rope_q_kernel(const __half* __restrict__ qpe,
                                                     const float2* __restrict__ cs,
                                                     __half* __restrict__ Qb, float qscale) {
  int i = blockIdx.x * 256 + threadIdx.x;  // 2048*32*32
  int row = i >> 10, rem = i & 1023, h = rem >> 5, j = rem & 31;
  float x0 = __half2float(qpe[(size_t)row * 2048 + h * 64 + 2 * j]);
  float x1 = __half2float(qpe[(size_t)row * 2048 + h * 64 + 2 * j + 1]);
  float2 c = cs[row * 32 + j];
  float o0 = (x0 * c.x - x1 * c.y) * qscale;
  float o1 = (x1 * c.x + x0 * c.y) * qscale;
  __half* dst = Qb + ((size_t)h * 2048 + row) * 192;
  dst[128 + j] = __float2half(o0);
  dst[160 + j] = __float2half(o1);
}

// ---------------- GEMM: C[M,N] = A[M,K](f16) x B[N,K](f16)^T ----------------
// 128xBN tile, BK=64, 4 waves 2x2, double-buffered LDS, 2-phase prefetch,
// XOR bank swizzle. EPI: 0=f32 store, 2=q_b split, 3=kv_b split (K nope + V^T)
template <int BN, int EPI>
__global__ __launch_bounds__(256) void gemm128(const __half* __restrict__ A, int lda,
                                               const __half* __restrict__ B, int K, int Ncols,
                                               float* __restrict__ Cf, int ldc,
                                               __half* __restrict__ O1, __half* __restrict__ O2,
                                               float qscale) {
  constexpr int NFR = BN / 32;  // B frags per wave: 4 (BN=128) or 6 (BN=192)
  __shared__ __align__(16) char As[2 * 128 * 128];
  __shared__ __align__(16) char Bs[2 * BN * 128];
  const int tid = threadIdx.x;
  const int lane = tid & 63, w = tid >> 6;
  const int l15 = lane & 15, g = lane >> 4;
  const int wr = w >> 1, wc = w & 1;
  // XCD-chunk swizzle (nwg % 8 == 0 for all launches)
  const int nwg = gridDim.x * gridDim.y;
  int wg = blockIdx.y * gridDim.x + blockIdx.x;
  wg = (wg & 7) * (nwg >> 3) + (wg >> 3);
  const int m0 = (wg / gridDim.x) * 128, n0 = (wg % gridDim.x) * BN;
  // staging geometry: chunks of 1KB (8 rows x 128B)
  const int srow = lane >> 3;                // row within chunk
  const int scol = ((lane & 7) ^ srow) * 8;  // pre-swizzled source col (halves)
  f32x4 acc[4][NFR] = {};
  const int nt = K >> 6;

  auto stage = [&](int t, int buf) {
    const __half* Ab = A + t * 64 + scol;
    const __half* Bb = B + t * 64 + scol;
#pragma unroll
    for (int cc = 0; cc < 4; ++cc) {
      int ch = w * 4 + cc;
      gload16(Ab + (size_t)(m0 + ch * 8 + srow) * lda, As + buf * 16384 + ch * 1024);
    }
#pragma unroll
    for (int cc = 0; cc < NFR; ++cc) {
      int ch = w * NFR + cc;
      gload16(Bb + (size_t)(n0 + ch * 8 + srow) * K, Bs + buf * (BN * 128) + ch * 1024);
    }
  };

  stage(0, 0);
  __syncthreads();

  for (int t = 0; t < nt; ++t) {
    const int buf = t & 1;
    if (t + 1 < nt) stage(t + 1, buf ^ 1);
    const char* Ab = As + buf * 16384;
    const char* Bb = Bs + buf * (BN * 128);
#pragma unroll
    for (int kk = 0; kk < 2; ++kk) {
      f16x8 af[4], bf[NFR];
#pragma unroll
      for (int m = 0; m < 4; ++m) {
        int r = wr * 64 + m * 16 + l15;
        af[m] = *(const f16x8*)(Ab + r * 128 + (((kk << 2) | g) ^ (r & 7)) * 16);
      }
#pragma unroll
      for (int n = 0; n < NFR; ++n) {
        int r = wc * (BN / 2) + n * 16 + l15;
        bf[n] = *(const f16x8*)(Bb + r * 128 + (((kk << 2) | g) ^ (r & 7)) * 16);
      }
#pragma unroll
      for (int m = 0; m < 4; ++m)
#pragma unroll
        for (int n = 0; n < NFR; ++n) acc[m][n] = mfma16(af[m], bf[n], acc[m][n]);
    }
    __syncthreads();  // drains stage(t+1); separates reads of buf from overwrite
  }

#pragma unroll
  for (int m = 0; m < 4; ++m)
#pragma unroll
    for (int n = 0; n < NFR; ++n)
#pragma unroll
      for (int i = 0; i < 4; ++i) {
        int row = m0 + wr * 64 + m * 16 + g * 4 + i;
        int col = n0 + wc * (BN / 2) + n * 16 + l15;
        float v = acc[m][n][i];
        if (EPI == 0) {
          if (col < Ncols) Cf[(size_t)row * ldc + col] = v;
        } else if (EPI == 2) {
          int h = col / 192, d = col - h * 192;
          if (d < 128)
            O1[((size_t)h * 2048 + row) * 192 + d] = __float2half(v * qscale);
          else
            O2[(size_t)row * 2048 + h * 64 + (d - 128)] = __float2half(v);
        } else if (EPI == 3) {
          int h = col >> 8, d = col & 255;
          if (d < 128)
            O1[((size_t)h * 2048 + row) * 192 + d] = __float2half(v);
          else
            O2[((size_t)h * 128 + (d - 128)) * 2048 + row] = __float2half(v);
        }
      }
}

// ---------------- Flash attention (2-phase pipelined, log2-domain softmax) ----
// grid (16 pairs, 32 heads); block does q-tiles pr and 31-pr (33 KV-iters).
// 4 waves; 16 q-rows/wave; KVB=64. K dbuf 2x24KB; V 18KB (rows 128..143 = ones
// so PV's 9th MFMA block accumulates the softmax denominator); P 9KB.
// Q pre-scaled by SCALE*log2e => p = exp2(s - m). Defer-max threshold 8.
__global__ __launch_bounds__(256) void attn_kernel(const __half* __restrict__ Q,
                                                   const __half* __restrict__ K,
                                                   const __half* __restrict__ Vt,
                                                   __half* __restrict__ Out) {
  __shared__ __align__(16) char Klds[2 * 64 * 384];  // 49152
  __shared__ __align__(16) char Vlds[144 * 128];     // 18432 (rows 128..143 ones)
  __shared__ __align__(16) __half Plds[4][16][72];   // 9216; total 76800 -> 2/CU
  int wg = blockIdx.y * gridDim.x + blockIdx.x;      // 512 blocks
  wg = (wg & 7) * 64 + (wg >> 3);
  const int pr = wg & 15, h = wg >> 4;
  const int tid = threadIdx.x, lane = tid & 63, w = tid >> 6;
  const int l15 = lane & 15, g = lane >> 4;

  const char* Kg = (const char*)(K + (size_t)h * 2048 * 192);
  const char* Vg = (const char*)(Vt + (size_t)h * 128 * 2048);

  // ones rows for the denominator MFMA (never overwritten by staging)
  if (tid < 128) {
    ((uint4*)(Vlds + 16384))[tid] =
        make_uint4(0x3C003C00u, 0x3C003C00u, 0x3C003C00u, 0x3C003C00u);
  }

  // per-wave K staging geometry (6 chunks of 1KB)
  int kL[6], kRow[6], kSS[6];
#pragma unroll
  for (int cc = 0; cc < 6; ++cc) {
    int c = w * 6 + cc;
    int L = c * 64 + lane;
    int row = (L * 2731) >> 16;  // L/24
    int slot = L - row * 24;
    kL[cc] = c;
    kRow[cc] = row;
    kSS[cc] = (slot & ~7) | ((slot ^ row) & 7);
  }

  for (int ht = 0; ht < 2; ++ht) {
    const int qt = ht ? (31 - pr) : pr;
    const int q0 = qt * 64;
    const int nt = qt + 1;

    const __half* Qh = Q + ((size_t)h * 2048 + q0 + w * 16 + l15) * 192;
    f16x8 qf[6];
#pragma unroll
    for (int kc = 0; kc < 6; ++kc) qf[kc] = *(const f16x8*)(Qh + kc * 32 + g * 8);

    f32x4 acc[9] = {};  // acc[8] = softmax denominator
    float m_i[4];
#pragma unroll
    for (int i = 0; i < 4; ++i) m_i[i] = -1e30f;

    // prologue: stage K(0) into buffer 0
#pragma unroll
    for (int cc = 0; cc < 6; ++cc)
      gload16(Kg + (size_t)kRow[cc] * 384 + kSS[cc] * 16, Klds + kL[cc] * 1024);
    __syncthreads();

    for (int t = 0; t < nt; ++t) {
      const int kv0 = t * 64;
      const char* Kcur = Klds + (t & 1) * 24576;

      // issue V(t) stage [128][64] f16, XOR-swizzled
#pragma unroll
      for (int cc = 0; cc < 4; ++cc) {
        int c = w * 4 + cc;
        int L = c * 64 + lane;
        int d = L >> 3, slot = L & 7;
        int ss = slot ^ (d & 7);
        gload16(Vg + ((size_t)d * 2048 + kv0) * 2 + ss * 16, Vlds + c * 1024);
      }
      // issue K(t+1) stage into other buffer
      if (t + 1 < nt) {
        char* Knxt = Klds + ((t + 1) & 1) * 24576;
#pragma unroll
        for (int cc = 0; cc < 6; ++cc)
          gload16(Kg + (size_t)(kv0 + 64 + kRow[cc]) * 384 + kSS[cc] * 16,
                  Knxt + kL[cc] * 1024);
      }

      // QK(t): S[16q x 64k] per wave
      f32x4 s[4] = {};
#pragma unroll
      for (int kc = 0; kc < 6; ++kc) {
#pragma unroll
        for (int n = 0; n < 4; ++n) {
          int krow = n * 16 + l15;
          int slot = kc * 4 + g;
          int ss = (slot & ~7) | ((slot ^ krow) & 7);
          f16x8 kf = *(const f16x8*)(Kcur + krow * 384 + ss * 16);
          s[n] = mfma16(qf[kc], kf, s[n]);
        }
      }

      const bool diag = (t == nt - 1);
      float ps[4][4];
      float mt[4] = {-1e30f, -1e30f, -1e30f, -1e30f};
#pragma unroll
      for (int n = 0; n < 4; ++n)
#pragma unroll
        for (int i = 0; i < 4; ++i) {
          float v = s[n][i];
          if (diag) {
            int key = n * 16 + l15, qq = w * 16 + g * 4 + i;
            if (key > qq) v = -1e30f;
          }
          ps[n][i] = v;
          mt[i] = fmaxf(mt[i], v);
        }
#pragma unroll
      for (int mm = 1; mm <= 8; mm <<= 1)
#pragma unroll
        for (int i = 0; i < 4; ++i) mt[i] = fmaxf(mt[i], __shfl_xor(mt[i], mm));

      // defer-max: rescale only when some row-max grew by > 8 (log2 domain)
      bool ok = true;
      float nm[4];
#pragma unroll
      for (int i = 0; i < 4; ++i) {
        nm[i] = fmaxf(m_i[i], mt[i]);
        ok = ok && (mt[i] - m_i[i] <= 8.0f);
      }
      if (!__all(ok)) {
#pragma unroll
        for (int i = 0; i < 4; ++i) {
          float c = exp2f(m_i[i] - nm[i]);
          m_i[i] = nm[i];
#pragma unroll
          for (int db = 0; db < 9; ++db) acc[db][i] *= c;
        }
      }
      // P = exp2(s - m) -> LDS (per-wave, private tile)
#pragma unroll
      for (int n = 0; n < 4; ++n)
#pragma unroll
        for (int i = 0; i < 4; ++i)
          Plds[w][g * 4 + i][n * 16 + l15] = __float2half(exp2f(ps[n][i] - m_i[i]));

      __syncthreads();  // drains V(t) [+K(t+1)] stages; all QK reads done

      // PV: out[16q x 144d] += P[16q x 64k] * V[64k x 144d] (last 16 = ones)
#pragma unroll
      for (int ks = 0; ks < 2; ++ks) {
        f16x8 pa = *(const f16x8*)((const char*)&Plds[w][0][0] + l15 * 144 + ks * 64 + g * 16);
#pragma unroll
        for (int db = 0; db < 9; ++db) {
          int d = db * 16 + l15;
          int ss = (ks * 4 + g) ^ (d & 7);
          f16x8 vf = *(const f16x8*)(Vlds + d * 128 + ss * 16);
          acc[db] = mfma16(pa, vf, acc[db]);
        }
      }
      __syncthreads();  // protect V/K buffer overwrite in next iteration
    }

#pragma unroll
    for (int i = 0; i < 4; ++i) {
      float inv = 1.0f / acc[8][i];
#pragma unroll
      for (int db = 0; db < 8; ++db) {
        int row = q0 + w * 16 + g * 4 + i;
        Out[(size_t)row * 4096 + h * 128 + db * 16 + l15] = __float2half(acc[db][i] * inv);
      }
    }
  }
}

// ---------------- launch ----------------
extern "C" void kernel_launch(void* const* d_in, const int* in_sizes, int n_in,
                              void* d_out, int out_size, void* d_ws, size_t ws_size,
                              hipStream_t stream) {
  (void)in_sizes; (void)n_in; (void)out_size; (void)ws_size;
  const float* hs = (const float*)d_in[0];
  const int* pos = (const int*)d_in[2];
  const float* q_a_w = (const float*)d_in[3];
  const float* q_a_ln = (const float*)d_in[4];
  const float* q_b_w = (const float*)d_in[5];
  const float* kv_a_w = (const float*)d_in[6];
  const float* kv_a_ln = (const float*)d_in[7];
  const float* kv_b_w = (const float*)d_in[8];
  const float* o_w = (const float*)d_in[9];

  char* p = (char*)d_ws;
  auto alloc = [&](size_t sz) { char* r = p; p += (sz + 255) & ~(size_t)255; return r; };
  __half* hs_h = (__half*)alloc((size_t)2048 * 4096 * 2);   // later aliased as attn_out
  __half* w_qab = (__half*)alloc((size_t)2176 * 4096 * 2);  // q_a 0..1535, kv_a 1536..2111
  __half* w_qb = (__half*)alloc((size_t)6144 * 1536 * 2);
  __half* w_kvb = (__half*)alloc((size_t)8192 * 512 * 2);
  float* qab_f = (float*)alloc((size_t)2048 * 2112 * 4);    // [2048][2112]
  __half* qa_r = (__half*)alloc((size_t)2048 * 1536 * 2);
  __half* kv_r = (__half*)alloc((size_t)2048 * 512 * 2);
  float2* cs_tab = (float2*)alloc((size_t)2048 * 32 * 8);
  __half* Qb = (__half*)alloc((size_t)32 * 2048 * 192 * 2);
  __half* Kb = (__half*)alloc((size_t)32 * 2048 * 192 * 2);
  __half* Vtb = (__half*)alloc((size_t)32 * 128 * 2048 * 2);
  __half* qpe = (__half*)alloc((size_t)2048 * 2048 * 2);
  __half* attn_h = hs_h;  // alias (hs_h dead after qab GEMM)
  __half* w_o = Qb;       // alias (Q/K dead after attention)

  // 192^-0.5 * (1+0.1*ln32)^2 * log2(e)  -> scores in log2 domain
  constexpr float QSCALE = 0.13086090981960297f * 1.4426950408889634f;

  cvt5_kernel<<<2048, 256, 0, stream>>>(hs, q_a_w, kv_a_w, q_b_w, kv_b_w,
                                        hs_h, w_qab, w_qab + (size_t)1536 * 4096,
                                        w_qb, w_kvb);
  rope_table_kernel<<<(2048 * 32) / 256, 256, 0, stream>>>(pos, cs_tab);

  // combined q_a + kv_a projection: [2048,4096] x [2112,4096]^T (BN=192, 176 blocks)
  gemm128<192, 0><<<dim3(11, 16), 256, 0, stream>>>(hs_h, 4096, w_qab, 4096, 2112, qab_f,
                                                    2112, nullptr, nullptr, 1.f);
  norm_rope_kernel<<<2048, 256, 0, stream>>>(qab_f, q_a_ln, kv_a_ln, cs_tab,
                                             qa_r, kv_r, Kb);
  gemm128<128, 2><<<dim3(48, 16), 256, 0, stream>>>(qa_r, 1536, w_qb, 1536, 6144, nullptr,
                                                    0, Qb, qpe, QSCALE);
  rope_q_kernel<<<(2048 * 1024) / 256, 256, 0, stream>>>(qpe, cs_tab, Qb, QSCALE);
  gemm128<128, 3><<<dim3(64, 16), 256, 0, stream>>>(kv_r, 512, w_kvb, 512, 8192, nullptr,
                                                    0, Kb, Vtb, 1.f);
  attn_kernel<<<dim3(16, 32), 256, 0, stream>>>(Qb, Kb, Vtb, attn_h);
  cvt_kernel<<<2048, 256, 0, stream>>>(o_w, w_o, (int)((size_t)4096 * 4096 / 4));
  gemm128<128, 0><<<dim3(32, 16), 256, 0, stream>>>(attn_h, 4096, w_o, 4096, 4096,
                                                    (float*)d_out, 4096, nullptr, nullptr,
                                                    1.f);
}